// Round 5
// baseline (509.345 us; speedup 1.0000x reference)
//
#include <hip/hip_runtime.h>

typedef unsigned short u16;
typedef __bf16 bf16x8 __attribute__((ext_vector_type(8)));
typedef float f32x4 __attribute__((ext_vector_type(4)));
typedef unsigned short us8 __attribute__((ext_vector_type(8)));
typedef unsigned short us4 __attribute__((ext_vector_type(4)));

#define B_ 4
#define S_ 2048
#define D_ 1024
#define H_ 16
#define HD_ 64
#define EPS_ 1e-5f
#define PSTR 72  // P LDS row stride (elems): >=64 (no aliasing for 64-key chunks), 144B rows -> 2-way banks (free)
#define SCALE_ (0.125f * 1.44269504088896341f)  // HD^-0.5 * log2(e); exp via exp2
#define THR_ 3.0f                               // defer-max threshold (log2 domain)

__device__ __forceinline__ u16 f2bf(float f) {
  unsigned u = __builtin_bit_cast(unsigned, f);
  u = (u + 0x7FFFu + ((u >> 16) & 1u)) >> 16;
  return (u16)u;
}

// tanh-form GELU via exp2: x - x/(1+t), t=exp2(c1*(x+c2*x^3)); |err| vs erf-GELU < 1e-3
__device__ __forceinline__ float gelu_f(float x) {
  float u = x * (2.3022388f + 0.10294971f * x * x);
  float te = __builtin_amdgcn_exp2f(u);
  return x - x * __builtin_amdgcn_rcpf(1.0f + te);
}

typedef const __attribute__((address_space(1))) unsigned int* gp1;
typedef __attribute__((address_space(3))) unsigned int* lp3;
__device__ __forceinline__ void gl_lds16(const void* g, void* l) {
  __builtin_amdgcn_global_load_lds((gp1)(unsigned long long)g,
                                   (lp3)(unsigned int)(unsigned long long)l,
                                   16, 0, 0);
}

// ---------------- weight transpose + f32->bf16 convert: W[K][N] -> Wt[N][K] ----------------
__global__ __launch_bounds__(256) void wconv_kernel(const float* __restrict__ W,
                                                    u16* __restrict__ Wt,
                                                    int Kd, int N) {
  __shared__ u16 tile[32][33];
  int bid = blockIdx.x;
  int nbn = N >> 5;
  int tk = bid / nbn, tn = bid % nbn;
  int tx = threadIdx.x & 31, ty = threadIdx.x >> 5;
#pragma unroll
  for (int i = 0; i < 4; i++) {
    int r = ty + i * 8;
    tile[r][tx] = f2bf(W[(size_t)(tk * 32 + r) * N + tn * 32 + tx]);
  }
  __syncthreads();
#pragma unroll
  for (int i = 0; i < 4; i++) {
    int r = ty + i * 8;
    Wt[(size_t)(tn * 32 + r) * Kd + tk * 32 + tx] = tile[tx][r];
  }
}

// ---------------- V transpose: Vc [bh][S][64] -> Vt [bh][64][S] ----------------------------
__global__ __launch_bounds__(256) void vtrans_kernel(const u16* __restrict__ Vc,
                                                     u16* __restrict__ Vt) {
  __shared__ u16 tile[64][72];
  int bh = blockIdx.x >> 5;
  int sb = blockIdx.x & 31;
  const u16* src = Vc + ((size_t)bh * S_ + sb * 64) * HD_;
  int r = threadIdx.x >> 2, c0 = (threadIdx.x & 3) * 16;
  *(us8*)&tile[r][c0] = *(const us8*)(src + r * HD_ + c0);
  *(us8*)&tile[r][c0 + 8] = *(const us8*)(src + r * HD_ + c0 + 8);
  __syncthreads();
  u16* dst = Vt + (size_t)bh * HD_ * S_ + sb * 64;
  int hd = threadIdx.x >> 2;
  int s0 = (threadIdx.x & 3) * 16;
  us8 a, b;
#pragma unroll
  for (int j = 0; j < 8; j++) a[j] = tile[s0 + j][hd];
#pragma unroll
  for (int j = 0; j < 8; j++) b[j] = tile[s0 + 8 + j][hd];
  *(us8*)(dst + (size_t)hd * S_ + s0) = a;
  *(us8*)(dst + (size_t)hd * S_ + s0 + 8) = b;
}

// ---------------- LayerNorm: f32 in -> bf16 out, one block per row (D=1024) ----------------
__global__ __launch_bounds__(256) void ln_kernel(const float* __restrict__ x,
                                                 const float* __restrict__ w,
                                                 const float* __restrict__ b,
                                                 u16* __restrict__ out) {
  int row = blockIdx.x;
  int t = threadIdx.x;
  int lane = t & 63, wid = t >> 6;
  const float4* xr = (const float4*)(x + (size_t)row * D_);
  float4 v = xr[t];
  float s = v.x + v.y + v.z + v.w;
  float q = v.x * v.x + v.y * v.y + v.z * v.z + v.w * v.w;
#pragma unroll
  for (int off = 1; off < 64; off <<= 1) {
    s += __shfl_xor(s, off);
    q += __shfl_xor(q, off);
  }
  __shared__ float red[8];
  if (lane == 0) { red[wid] = s; red[4 + wid] = q; }
  __syncthreads();
  s = red[0] + red[1] + red[2] + red[3];
  q = red[4] + red[5] + red[6] + red[7];
  float mu = s * (1.0f / D_);
  float var = q * (1.0f / D_) - mu * mu;
  float rs = rsqrtf(var + EPS_);
  int c = t * 4;
  float4 wv = *(const float4*)(w + c);
  float4 bv = *(const float4*)(b + c);
  us4 o;
  o[0] = f2bf((v.x - mu) * rs * wv.x + bv.x);
  o[1] = f2bf((v.y - mu) * rs * wv.y + bv.y);
  o[2] = f2bf((v.z - mu) * rs * wv.z + bv.z);
  o[3] = f2bf((v.w - mu) * rs * wv.w + bv.w);
  *(us4*)(out + (size_t)row * D_ + c) = o;
}

// ---------------- GEMM: BK=64, T2 XOR-swizzled LDS (pre-swizzled global src, linear dest) --
// MODE bits: 1=bias, 2=gelu, 4=residual(f32), 8=bf16 out, 16=QKV interleaved split store
template <int MODE>
__global__ __launch_bounds__(256) void gemm_kernel(
    const u16* __restrict__ A, const u16* __restrict__ Bt,
    const float* __restrict__ bias, const float* __restrict__ res,
    float* __restrict__ Cf, u16* __restrict__ Cb,
    u16* __restrict__ Qc, u16* __restrict__ Kc, u16* __restrict__ Vc,
    int M, int N, int K) {
  __shared__ __align__(16) u16 Al[128 * 64];
  __shared__ __align__(16) u16 Bl[128 * 64];
  int t = threadIdx.x;
  int nbn = N >> 7;
  int nwg = gridDim.x;
  int cpx = nwg >> 3;
  int bid = (blockIdx.x % 8) * cpx + blockIdx.x / 8;
  int bm = bid / nbn, bn = bid % nbn;
  int lane = t & 63, wid = t >> 6;
  int wm = wid >> 1, wn = wid & 1;
  int lrow = lane & 15, lgr = lane >> 4;
  const u16* Ab = A + (size_t)bm * 128 * K;
  const u16* Bb = Bt + (size_t)bn * 128 * K;
  // staging: instr j (0..3), wave w: rows [(j*4+w)*8, +8). lane l -> row +=(l>>3),
  // swizzled source col slot ((l&7)^(l>>3)); LDS dest stays linear (gl_lds requirement).
  int sr = lane >> 3;
  int sc = ((lane & 7) ^ sr) << 3;  // elems
  const u16* Ag[4];
  const u16* Bg[4];
  u16* Ald[4];
  u16* Bld[4];
#pragma unroll
  for (int j = 0; j < 4; j++) {
    int row0 = (j * 4 + wid) * 8;
    Ag[j] = Ab + (size_t)(row0 + sr) * K + sc;
    Bg[j] = Bb + (size_t)(row0 + sr) * K + sc;
    Ald[j] = &Al[row0 * 64 + lane * 8];
    Bld[j] = &Bl[row0 * 64 + lane * 8];
  }
  int sl7 = lrow & 7;  // row&7 for all fragment rows this lane reads
  f32x4 acc[4][4] = {};
  for (int k0 = 0; k0 < K; k0 += 64) {
#pragma unroll
    for (int j = 0; j < 4; j++) {
      gl_lds16(Ag[j] + k0, Ald[j]);
      gl_lds16(Bg[j] + k0, Bld[j]);
    }
    __syncthreads();  // drains vmcnt(0): tile resident
    bf16x8 af[2][4], bfr[2][4];
#pragma unroll
    for (int ks = 0; ks < 2; ks++) {
      int slot = ((ks << 2) | lgr) ^ sl7;  // 16B slot after swizzle
#pragma unroll
      for (int m = 0; m < 4; m++)
        af[ks][m] = *(const bf16x8*)&Al[(wm * 64 + m * 16 + lrow) * 64 + slot * 8];
#pragma unroll
      for (int n = 0; n < 4; n++)
        bfr[ks][n] = *(const bf16x8*)&Bl[(wn * 64 + n * 16 + lrow) * 64 + slot * 8];
    }
#pragma unroll
    for (int m = 0; m < 4; m++)
#pragma unroll
      for (int n = 0; n < 4; n++) {
        acc[m][n] = __builtin_amdgcn_mfma_f32_16x16x32_bf16(af[0][m], bfr[0][n], acc[m][n], 0, 0, 0);
        acc[m][n] = __builtin_amdgcn_mfma_f32_16x16x32_bf16(af[1][m], bfr[1][n], acc[m][n], 0, 0, 0);
      }
    __syncthreads();  // all waves done reading before next overwrite
  }
  // epilogue: n outer so col-derived address math is hoisted
#pragma unroll
  for (int n = 0; n < 4; n++) {
    int col = bn * 128 + wn * 64 + n * 16 + lrow;
    float bv = (MODE & 1) ? bias[col] : 0.0f;
    if (MODE & 16) {
      // col factors as (h, hd, c) with c fastest; c=0:K, c=1:Q, c=2:V (all [bh][S][64])
      int c = col % 3;
      int hd = (col / 3) & 63;
      int h = col / 192;
      u16* dst = (c == 0) ? Kc : (c == 1) ? Qc : Vc;
#pragma unroll
      for (int m = 0; m < 4; m++)
#pragma unroll
        for (int r = 0; r < 4; r++) {
          int row = bm * 128 + wm * 64 + m * 16 + lgr * 4 + r;
          int bb = row >> 11, sIdx = row & 2047;
          dst[(((size_t)(bb * H_ + h)) * S_ + sIdx) * HD_ + hd] = f2bf(acc[m][n][r]);
        }
    } else {
#pragma unroll
      for (int m = 0; m < 4; m++)
#pragma unroll
        for (int r = 0; r < 4; r++) {
          int row = bm * 128 + wm * 64 + m * 16 + lgr * 4 + r;
          float v = acc[m][n][r] + bv;
          if (MODE & 2) v = gelu_f(v);
          if (MODE & 4) v += res[(size_t)row * N + col];
          if (MODE & 8) Cb[(size_t)row * N + col] = f2bf(v);
          else          Cf[(size_t)row * N + col] = v;
        }
    }
  }
}

// ---------------- causal flash attention -------------------------------------------------
// Q,K [bh][S][64] bf16, Vt [bh][64][S] bf16. One wave per 32 q rows.
// Tail chunks (32-key): original structure.
template <int NK, bool MASK>
__device__ __forceinline__ void attn_chunk(
    const u16* __restrict__ Kh, const u16* __restrict__ Vh, u16* PlW,
    const bf16x8 (&qf)[2][2], f32x4 (&o)[2][4],
    float (&mrun)[2][4], float (&lrun)[2][4],
    int kb, int qbase, int lrow, int lgr) {
  bf16x8 kf[NK][2];
#pragma unroll
  for (int ki = 0; ki < NK; ki++)
#pragma unroll
    for (int h = 0; h < 2; h++)
      kf[ki][h] = *(const bf16x8*)(Kh + (size_t)(kb + ki * 16 + lrow) * HD_ + h * 32 + lgr * 8);
  f32x4 s[2][NK];
  __builtin_amdgcn_s_setprio(1);
#pragma unroll
  for (int qi = 0; qi < 2; qi++)
#pragma unroll
    for (int ki = 0; ki < NK; ki++) {
      f32x4 z = {0.f, 0.f, 0.f, 0.f};
      z = __builtin_amdgcn_mfma_f32_16x16x32_bf16(qf[qi][0], kf[ki][0], z, 0, 0, 0);
      z = __builtin_amdgcn_mfma_f32_16x16x32_bf16(qf[qi][1], kf[ki][1], z, 0, 0, 0);
      s[qi][ki] = z;
    }
  __builtin_amdgcn_s_setprio(0);
  float rm[2][4];
  bool ok = true;
#pragma unroll
  for (int qi = 0; qi < 2; qi++)
#pragma unroll
    for (int r = 0; r < 4; r++) {
      float m0 = -3.0e38f;
#pragma unroll
      for (int ki = 0; ki < NK; ki++) {
        float v = s[qi][ki][r] * SCALE_;
        if (MASK) {
          int qrow = qbase + qi * 16 + lgr * 4 + r;
          int kcol = kb + ki * 16 + lrow;
          if (kcol > qrow) v = -3.0e38f;
        }
        s[qi][ki][r] = v;
        m0 = fmaxf(m0, v);
      }
      rm[qi][r] = m0;
      ok = ok && (m0 <= mrun[qi][r] + THR_);
    }
  if (__all(ok)) {
#pragma unroll
    for (int qi = 0; qi < 2; qi++)
#pragma unroll
      for (int r = 0; r < 4; r++) {
        float m = mrun[qi][r];
        float lacc = lrun[qi][r];
#pragma unroll
        for (int ki = 0; ki < NK; ki++) {
          float p = __builtin_amdgcn_exp2f(s[qi][ki][r] - m);
          lacc += p;
          PlW[qi * (16 * PSTR) + (lgr * 4 + r) * PSTR + ki * 16 + lrow] = f2bf(p);
        }
        lrun[qi][r] = lacc;
      }
  } else {
#pragma unroll
    for (int qi = 0; qi < 2; qi++) {
      float corr[4];
#pragma unroll
      for (int r = 0; r < 4; r++) {
        float m0 = rm[qi][r];
#pragma unroll
        for (int off = 1; off < 16; off <<= 1) m0 = fmaxf(m0, __shfl_xor(m0, off));
        float mnew = fmaxf(mrun[qi][r], m0);
        float c = __builtin_amdgcn_exp2f(mrun[qi][r] - mnew);
        corr[r] = c;
        mrun[qi][r] = mnew;
        float lacc = lrun[qi][r] * c;
#pragma unroll
        for (int ki = 0; ki < NK; ki++) {
          float p = __builtin_amdgcn_exp2f(s[qi][ki][r] - mnew);
          lacc += p;
          PlW[qi * (16 * PSTR) + (lgr * 4 + r) * PSTR + ki * 16 + lrow] = f2bf(p);
        }
        lrun[qi][r] = lacc;
      }
#pragma unroll
      for (int nb = 0; nb < 4; nb++)
#pragma unroll
        for (int r = 0; r < 4; r++) o[qi][nb][r] *= corr[r];
    }
  }
#pragma unroll
  for (int sub = 0; sub < NK / 2; sub++) {
    bf16x8 pf0 = *(const bf16x8*)&PlW[0 * (16 * PSTR) + lrow * PSTR + sub * 32 + lgr * 8];
    bf16x8 pf1 = *(const bf16x8*)&PlW[1 * (16 * PSTR) + lrow * PSTR + sub * 32 + lgr * 8];
    __builtin_amdgcn_s_setprio(1);
#pragma unroll
    for (int nb = 0; nb < 4; nb++) {
      bf16x8 vf = *(const bf16x8*)(Vh + (size_t)(nb * 16 + lrow) * S_ + kb + sub * 32 + lgr * 8);
      o[0][nb] = __builtin_amdgcn_mfma_f32_16x16x32_bf16(pf0, vf, o[0][nb], 0, 0, 0);
      o[1][nb] = __builtin_amdgcn_mfma_f32_16x16x32_bf16(pf1, vf, o[1][nb], 0, 0, 0);
    }
    __builtin_amdgcn_s_setprio(0);
  }
}

__global__ __launch_bounds__(64) void attn_kernel(const u16* __restrict__ Q,
                                                  const u16* __restrict__ Kk,
                                                  const u16* __restrict__ Vt,
                                                  u16* __restrict__ ctx) {
  __shared__ __align__(16) u16 Pl[2][16 * PSTR];
  int t = threadIdx.x, lane = t & 63;
  int strip = (S_ / 32) - 1 - (int)(blockIdx.x >> 6);
  int bh = blockIdx.x & 63;
  int b = bh >> 4, h = bh & 15;
  const u16* Qh = Q + (size_t)bh * S_ * HD_;
  const u16* Kh = Kk + (size_t)bh * S_ * HD_;
  const u16* Vh = Vt + (size_t)bh * HD_ * S_;
  u16* PlW = &Pl[0][0];
  int qbase = strip * 32;
  int lrow = lane & 15, lgr = lane >> 4;

  bf16x8 qf[2][2];
#pragma unroll
  for (int qi = 0; qi < 2; qi++)
#pragma unroll
    for (int kb = 0; kb < 2; kb++)
      qf[qi][kb] = *(const bf16x8*)(Qh + (size_t)(qbase + qi * 16 + lrow) * HD_ + kb * 32 + lgr * 8);

  f32x4 o[2][4] = {};
  float mrun[2][4], lrun[2][4];
#pragma unroll
  for (int qi = 0; qi < 2; qi++)
#pragma unroll
    for (int r = 0; r < 4; r++) { mrun[qi][r] = -1e30f; lrun[qi][r] = 0.f; }

  const u16* Kbase = Kh + (size_t)lrow * HD_ + lgr * 8;
  const u16* Vbase = Vh + (size_t)lrow * S_ + lgr * 8;

  // ---- bulk: 64-key unmasked chunks with K-prefetch rotation + V hoist ----
  int nf64 = qbase >> 6;
  bf16x8 kf[4][2];
  if (nf64 > 0) {
#pragma unroll
    for (int ki = 0; ki < 4; ki++)
#pragma unroll
      for (int hh = 0; hh < 2; hh++)
        kf[ki][hh] = *(const bf16x8*)(Kbase + (size_t)(ki * 16) * HD_ + hh * 32);
  }
  for (int kt = 0; kt < nf64; kt++) {
    int kb = kt * 64;
    f32x4 s[2][4];
    __builtin_amdgcn_s_setprio(1);
#pragma unroll
    for (int qi = 0; qi < 2; qi++)
#pragma unroll
      for (int ki = 0; ki < 4; ki++) {
        f32x4 z = {0.f, 0.f, 0.f, 0.f};
        z = __builtin_amdgcn_mfma_f32_16x16x32_bf16(qf[qi][0], kf[ki][0], z, 0, 0, 0);
        z = __builtin_amdgcn_mfma_f32_16x16x32_bf16(qf[qi][1], kf[ki][1], z, 0, 0, 0);
        s[qi][ki] = z;
      }
    __builtin_amdgcn_s_setprio(0);
    // prefetch next chunk's K (kf regs free after QK^T; hides latency under softmax+PV)
    if (kt + 1 < nf64) {
      const u16* kn = Kbase + (size_t)(kb + 64) * HD_;
#pragma unroll
      for (int ki = 0; ki < 4; ki++)
#pragma unroll
        for (int hh = 0; hh < 2; hh++)
          kf[ki][hh] = *(const bf16x8*)(kn + (size_t)(ki * 16) * HD_ + hh * 32);
    }
    // hoist V loads for sub 0 (consumed right after softmax)
    bf16x8 vf0[4];
#pragma unroll
    for (int nb = 0; nb < 4; nb++)
      vf0[nb] = *(const bf16x8*)(Vbase + (size_t)(nb * 16) * S_ + kb);
    // softmax: defer-max fast/slow; max on raw scores (scale>0 monotone), exp via fma-fold
    float m0r[2][4];
    bool ok = true;
#pragma unroll
    for (int qi = 0; qi < 2; qi++)
#pragma unroll
      for (int r = 0; r < 4; r++) {
        float m0 = fmaxf(fmaxf(s[qi][0][r], s[qi][1][r]), fmaxf(s[qi][2][r], s[qi][3][r]));
        m0r[qi][r] = m0;
        ok = ok && (m0 * SCALE_ <= mrun[qi][r] + THR_);
      }
    if (__all(ok)) {
#pragma unroll
      for (int qi = 0; qi < 2; qi++)
#pragma unroll
        for (int r = 0; r < 4; r++) {
          float m = mrun[qi][r];
          float lacc = lrun[qi][r];
#pragma unroll
          for (int ki = 0; ki < 4; ki++) {
            float p = __builtin_amdgcn_exp2f(__builtin_fmaf(s[qi][ki][r], SCALE_, -m));
            lacc += p;
            PlW[qi * (16 * PSTR) + (lgr * 4 + r) * PSTR + ki * 16 + lrow] = f2bf(p);
          }
          lrun[qi][r] = lacc;
        }
    } else {
#pragma unroll
      for (int qi = 0; qi < 2; qi++) {
        float corr[4];
#pragma unroll
        for (int r = 0; r < 4; r++) {
          float m0 = m0r[qi][r];
#pragma unroll
          for (int off = 1; off < 16; off <<= 1) m0 = fmaxf(m0, __shfl_xor(m0, off));
          float mnew = fmaxf(mrun[qi][r], m0 * SCALE_);
          float c = __builtin_amdgcn_exp2f(mrun[qi][r] - mnew);
          corr[r] = c;
          mrun[qi][r] = mnew;
          float lacc = lrun[qi][r] * c;
#pragma unroll
          for (int ki = 0; ki < 4; ki++) {
            float p = __builtin_amdgcn_exp2f(__builtin_fmaf(s[qi][ki][r], SCALE_, -mnew));
            lacc += p;
            PlW[qi * (16 * PSTR) + (lgr * 4 + r) * PSTR + ki * 16 + lrow] = f2bf(p);
          }
          lrun[qi][r] = lacc;
        }
#pragma unroll
        for (int nb = 0; nb < 4; nb++)
#pragma unroll
          for (int r = 0; r < 4; r++) o[qi][nb][r] *= corr[r];
      }
    }
    // PV sub 0 (vf0 already in flight)
    {
      bf16x8 pf0 = *(const bf16x8*)&PlW[0 * (16 * PSTR) + lrow * PSTR + lgr * 8];
      bf16x8 pf1 = *(const bf16x8*)&PlW[1 * (16 * PSTR) + lrow * PSTR + lgr * 8];
      __builtin_amdgcn_s_setprio(1);
#pragma unroll
      for (int nb = 0; nb < 4; nb++) {
        o[0][nb] = __builtin_amdgcn_mfma_f32_16x16x32_bf16(pf0, vf0[nb], o[0][nb], 0, 0, 0);
        o[1][nb] = __builtin_amdgcn_mfma_f32_16x16x32_bf16(pf1, vf0[nb], o[1][nb], 0, 0, 0);
      }
      __builtin_amdgcn_s_setprio(0);
    }
    // PV sub 1
    {
      bf16x8 pf0 = *(const bf16x8*)&PlW[0 * (16 * PSTR) + lrow * PSTR + 32 + lgr * 8];
      bf16x8 pf1 = *(const bf16x8*)&PlW[1 * (16 * PSTR) + lrow * PSTR + 32 + lgr * 8];
      __builtin_amdgcn_s_setprio(1);
#pragma unroll
      for (int nb = 0; nb < 4; nb++) {
        bf16x8 vf = *(const bf16x8*)(Vbase + (size_t)(nb * 16) * S_ + kb + 32);
        o[0][nb] = __builtin_amdgcn_mfma_f32_16x16x32_bf16(pf0, vf, o[0][nb], 0, 0, 0);
        o[1][nb] = __builtin_amdgcn_mfma_f32_16x16x32_bf16(pf1, vf, o[1][nb], 0, 0, 0);
      }
      __builtin_amdgcn_s_setprio(0);
    }
  }

  // ---- tails: optional 32-key unmasked + 32-key masked diagonal ----
  if (qbase & 32)
    attn_chunk<2, false>(Kh, Vh, PlW, qf, o, mrun, lrun, qbase - 32, qbase, lrow, lgr);
  attn_chunk<2, true>(Kh, Vh, PlW, qf, o, mrun, lrun, qbase, qbase, lrow, lgr);

#pragma unroll
  for (int qi = 0; qi < 2; qi++) {
#pragma unroll
    for (int r = 0; r < 4; r++) {
      float l = lrun[qi][r];
#pragma unroll
      for (int off = 1; off < 16; off <<= 1) l += __shfl_xor(l, off);
      float inv = 1.0f / l;
      int srow = qbase + qi * 16 + lgr * 4 + r;
      size_t base = ((size_t)b * S_ + srow) * D_ + h * HD_;
#pragma unroll
      for (int nb = 0; nb < 4; nb++)
        ctx[base + nb * 16 + lrow] = f2bf(o[qi][nb][r] * inv);
    }
  }
}

extern "C" void kernel_launch(void* const* d_in, const int* in_sizes, int n_in,
                              void* d_out, int out_size, void* d_ws, size_t ws_size,
                              hipStream_t stream) {
  const float* x = (const float*)d_in[0];
  const float* ln1w = (const float*)d_in[1];
  const float* ln1b = (const float*)d_in[2];
  const float* wqkv = (const float*)d_in[3];
  const float* wproj = (const float*)d_in[4];
  const float* bproj = (const float*)d_in[5];
  const float* ln2w = (const float*)d_in[6];
  const float* ln2b = (const float*)d_in[7];
  const float* wff1 = (const float*)d_in[8];
  const float* bff1 = (const float*)d_in[9];
  const float* wff2 = (const float*)d_in[10];
  const float* bff2 = (const float*)d_in[11];

  char* ws = (char*)d_ws;
  u16* wqkvT = (u16*)(ws + 0);                 //  6 MB  [3072][1024]
  u16* wprojT = (u16*)(ws + 6291456);          //  2 MB  [1024][1024]
  u16* wff1T = (u16*)(ws + 8388608);           //  8 MB  [4096][1024]
  u16* wff2T = (u16*)(ws + 16777216);          //  8 MB  [1024][4096]
  u16* h1 = (u16*)(ws + 25165824);             // 16 MB  [8192][1024]; dead after QKV gemm
  u16* Vt = (u16*)(ws + 25165824);             // 16 MB  [bh][64][S]; written after h1 dead
  u16* Qc = (u16*)(ws + 41943040);             // 16 MB  [bh][S][64]
  u16* Kc = (u16*)(ws + 58720256);             // 16 MB
  u16* Vc = (u16*)(ws + 75497472);             // 16 MB  [bh][S][64]
  u16* ctx = (u16*)(ws + 92274688);            // 16 MB  [8192][1024]
  float* x1 = (float*)(ws + 109051904);        // 32 MB  [8192][1024]
  u16* h2 = (u16*)(ws + 142606336);            // 16 MB
  u16* g = (u16*)(ws + 25165824);              // 64 MB  [8192][4096]; overlays h1/Vt/Qc/Kc/Vc
  float* outp = (float*)d_out;

  wconv_kernel<<<(1024 / 32) * (3072 / 32), 256, 0, stream>>>(wqkv, wqkvT, 1024, 3072);
  wconv_kernel<<<(1024 / 32) * (1024 / 32), 256, 0, stream>>>(wproj, wprojT, 1024, 1024);
  wconv_kernel<<<(1024 / 32) * (4096 / 32), 256, 0, stream>>>(wff1, wff1T, 1024, 4096);
  wconv_kernel<<<(4096 / 32) * (1024 / 32), 256, 0, stream>>>(wff2, wff2T, 4096, 1024);

  ln_kernel<<<8192, 256, 0, stream>>>(x, ln1w, ln1b, h1);
  gemm_kernel<16><<<64 * 24, 256, 0, stream>>>(h1, wqkvT, nullptr, nullptr, nullptr, nullptr,
                                               Qc, Kc, Vc, 8192, 3072, 1024);
  vtrans_kernel<<<64 * 32, 256, 0, stream>>>(Vc, Vt);
  attn_kernel<<<64 * (S_ / 32), 64, 0, stream>>>(Qc, Kc, Vt, ctx);
  gemm_kernel<5><<<64 * 8, 256, 0, stream>>>(ctx, wprojT, bproj, x, x1, nullptr,
                                             nullptr, nullptr, nullptr, 8192, 1024, 1024);
  ln_kernel<<<8192, 256, 0, stream>>>(x1, ln2w, ln2b, h2);
  gemm_kernel<11><<<64 * 32, 256, 0, stream>>>(h2, wff1T, bff1, nullptr, nullptr, g,
                                               nullptr, nullptr, nullptr, 8192, 4096, 1024);
  gemm_kernel<5><<<64 * 8, 256, 0, stream>>>(g, wff2T, bff2, x1, outp, nullptr,
                                             nullptr, nullptr, nullptr, 8192, 1024, 4096);
}

// Round 6
// 487.904 us; speedup vs baseline: 1.0439x; 1.0439x over previous
//
#include <hip/hip_runtime.h>

typedef unsigned short u16;
typedef unsigned int u32;
typedef __bf16 bf16x8 __attribute__((ext_vector_type(8)));
typedef float f32x4 __attribute__((ext_vector_type(4)));
typedef float f32x16 __attribute__((ext_vector_type(16)));
typedef unsigned short us8 __attribute__((ext_vector_type(8)));
typedef unsigned short us4 __attribute__((ext_vector_type(4)));
typedef unsigned int u32x4 __attribute__((ext_vector_type(4)));

#define B_ 4
#define S_ 2048
#define D_ 1024
#define H_ 16
#define HD_ 64
#define EPS_ 1e-5f
#define SCALE_ (0.125f * 1.44269504088896341f)  // HD^-0.5 * log2(e); exp via exp2
#define THR_ 3.0f                               // defer-max threshold (log2 domain)

__device__ __forceinline__ u16 f2bf(float f) {
  unsigned u = __builtin_bit_cast(unsigned, f);
  u = (u + 0x7FFFu + ((u >> 16) & 1u)) >> 16;
  return (u16)u;
}

// tanh-form GELU via exp2: x - x/(1+t), t=exp2(c1*(x+c2*x^3)); |err| vs erf-GELU < 1e-3
__device__ __forceinline__ float gelu_f(float x) {
  float u = x * (2.3022388f + 0.10294971f * x * x);
  float te = __builtin_amdgcn_exp2f(u);
  return x - x * __builtin_amdgcn_rcpf(1.0f + te);
}

typedef const __attribute__((address_space(1))) unsigned int* gp1;
typedef __attribute__((address_space(3))) unsigned int* lp3;
__device__ __forceinline__ void gl_lds16(const void* g, void* l) {
  __builtin_amdgcn_global_load_lds((gp1)(unsigned long long)g,
                                   (lp3)(unsigned int)(unsigned long long)l,
                                   16, 0, 0);
}

__device__ __forceinline__ u32 cvtpk_bf16(float lo, float hi) {
  u32 d;
  asm("v_cvt_pk_bf16_f32 %0, %1, %2" : "=v"(d) : "v"(lo), "v"(hi));
  return d;
}
// swaps a's lanes 32-63 with b's lanes 0-31: a' = [a.lo | b.lo], b' = [a.hi | b.hi]
__device__ __forceinline__ void swap32(u32& a, u32& b) {
  asm("v_permlane32_swap_b32 %0, %1" : "+v"(a), "+v"(b));
}

__device__ __forceinline__ f32x16 zero16() {
  f32x16 z;
#pragma unroll
  for (int i = 0; i < 16; i++) z[i] = 0.f;
  return z;
}

// ---------------- weight transpose + f32->bf16 convert: W[K][N] -> Wt[N][K] ----------------
__global__ __launch_bounds__(256) void wconv_kernel(const float* __restrict__ W,
                                                    u16* __restrict__ Wt,
                                                    int Kd, int N) {
  __shared__ u16 tile[32][33];
  int bid = blockIdx.x;
  int nbn = N >> 5;
  int tk = bid / nbn, tn = bid % nbn;
  int tx = threadIdx.x & 31, ty = threadIdx.x >> 5;
#pragma unroll
  for (int i = 0; i < 4; i++) {
    int r = ty + i * 8;
    tile[r][tx] = f2bf(W[(size_t)(tk * 32 + r) * N + tn * 32 + tx]);
  }
  __syncthreads();
#pragma unroll
  for (int i = 0; i < 4; i++) {
    int r = ty + i * 8;
    Wt[(size_t)(tn * 32 + r) * Kd + tk * 32 + tx] = tile[tx][r];
  }
}

// ---------------- V transpose: Vc [bh][S][64] -> Vt [bh][64][S] ----------------------------
__global__ __launch_bounds__(256) void vtrans_kernel(const u16* __restrict__ Vc,
                                                     u16* __restrict__ Vt) {
  __shared__ u16 tile[64][72];
  int bh = blockIdx.x >> 5;
  int sb = blockIdx.x & 31;
  const u16* src = Vc + ((size_t)bh * S_ + sb * 64) * HD_;
  int r = threadIdx.x >> 2, c0 = (threadIdx.x & 3) * 16;
  *(us8*)&tile[r][c0] = *(const us8*)(src + r * HD_ + c0);
  *(us8*)&tile[r][c0 + 8] = *(const us8*)(src + r * HD_ + c0 + 8);
  __syncthreads();
  u16* dst = Vt + (size_t)bh * HD_ * S_ + sb * 64;
  int hd = threadIdx.x >> 2;
  int s0 = (threadIdx.x & 3) * 16;
  us8 a, b;
#pragma unroll
  for (int j = 0; j < 8; j++) a[j] = tile[s0 + j][hd];
#pragma unroll
  for (int j = 0; j < 8; j++) b[j] = tile[s0 + 8 + j][hd];
  *(us8*)(dst + (size_t)hd * S_ + s0) = a;
  *(us8*)(dst + (size_t)hd * S_ + s0 + 8) = b;
}

// ---------------- LayerNorm: f32 in -> bf16 out, one block per row (D=1024) ----------------
__global__ __launch_bounds__(256) void ln_kernel(const float* __restrict__ x,
                                                 const float* __restrict__ w,
                                                 const float* __restrict__ b,
                                                 u16* __restrict__ out) {
  int row = blockIdx.x;
  int t = threadIdx.x;
  int lane = t & 63, wid = t >> 6;
  const float4* xr = (const float4*)(x + (size_t)row * D_);
  float4 v = xr[t];
  float s = v.x + v.y + v.z + v.w;
  float q = v.x * v.x + v.y * v.y + v.z * v.z + v.w * v.w;
#pragma unroll
  for (int off = 1; off < 64; off <<= 1) {
    s += __shfl_xor(s, off);
    q += __shfl_xor(q, off);
  }
  __shared__ float red[8];
  if (lane == 0) { red[wid] = s; red[4 + wid] = q; }
  __syncthreads();
  s = red[0] + red[1] + red[2] + red[3];
  q = red[4] + red[5] + red[6] + red[7];
  float mu = s * (1.0f / D_);
  float var = q * (1.0f / D_) - mu * mu;
  float rs = rsqrtf(var + EPS_);
  int c = t * 4;
  float4 wv = *(const float4*)(w + c);
  float4 bv = *(const float4*)(b + c);
  us4 o;
  o[0] = f2bf((v.x - mu) * rs * wv.x + bv.x);
  o[1] = f2bf((v.y - mu) * rs * wv.y + bv.y);
  o[2] = f2bf((v.z - mu) * rs * wv.z + bv.z);
  o[3] = f2bf((v.w - mu) * rs * wv.w + bv.w);
  *(us4*)(out + (size_t)row * D_ + c) = o;
}

// ---------------- GEMM: BK=64, T2 XOR-swizzled LDS (pre-swizzled global src, linear dest) --
// MODE bits: 1=bias, 2=gelu, 4=residual(f32), 8=bf16 out, 16=QKV interleaved split store
template <int MODE>
__global__ __launch_bounds__(256) void gemm_kernel(
    const u16* __restrict__ A, const u16* __restrict__ Bt,
    const float* __restrict__ bias, const float* __restrict__ res,
    float* __restrict__ Cf, u16* __restrict__ Cb,
    u16* __restrict__ Qc, u16* __restrict__ Kc, u16* __restrict__ Vc,
    int M, int N, int K) {
  __shared__ __align__(16) u16 Al[128 * 64];
  __shared__ __align__(16) u16 Bl[128 * 64];
  int t = threadIdx.x;
  int nbn = N >> 7;
  int nwg = gridDim.x;
  int cpx = nwg >> 3;
  int bid = (blockIdx.x % 8) * cpx + blockIdx.x / 8;
  int bm = bid / nbn, bn = bid % nbn;
  int lane = t & 63, wid = t >> 6;
  int wm = wid >> 1, wn = wid & 1;
  int lrow = lane & 15, lgr = lane >> 4;
  const u16* Ab = A + (size_t)bm * 128 * K;
  const u16* Bb = Bt + (size_t)bn * 128 * K;
  // staging: instr j (0..3), wave w: rows [(j*4+w)*8, +8). lane l -> row +=(l>>3),
  // swizzled source col slot ((l&7)^(l>>3)); LDS dest stays linear (gl_lds requirement).
  int sr = lane >> 3;
  int sc = ((lane & 7) ^ sr) << 3;  // elems
  const u16* Ag[4];
  const u16* Bg[4];
  u16* Ald[4];
  u16* Bld[4];
#pragma unroll
  for (int j = 0; j < 4; j++) {
    int row0 = (j * 4 + wid) * 8;
    Ag[j] = Ab + (size_t)(row0 + sr) * K + sc;
    Bg[j] = Bb + (size_t)(row0 + sr) * K + sc;
    Ald[j] = &Al[row0 * 64 + lane * 8];
    Bld[j] = &Bl[row0 * 64 + lane * 8];
  }
  int sl7 = lrow & 7;  // row&7 for all fragment rows this lane reads
  f32x4 acc[4][4] = {};
  for (int k0 = 0; k0 < K; k0 += 64) {
#pragma unroll
    for (int j = 0; j < 4; j++) {
      gl_lds16(Ag[j] + k0, Ald[j]);
      gl_lds16(Bg[j] + k0, Bld[j]);
    }
    __syncthreads();  // drains vmcnt(0): tile resident
    bf16x8 af[2][4], bfr[2][4];
#pragma unroll
    for (int ks = 0; ks < 2; ks++) {
      int slot = ((ks << 2) | lgr) ^ sl7;  // 16B slot after swizzle
#pragma unroll
      for (int m = 0; m < 4; m++)
        af[ks][m] = *(const bf16x8*)&Al[(wm * 64 + m * 16 + lrow) * 64 + slot * 8];
#pragma unroll
      for (int n = 0; n < 4; n++)
        bfr[ks][n] = *(const bf16x8*)&Bl[(wn * 64 + n * 16 + lrow) * 64 + slot * 8];
    }
#pragma unroll
    for (int m = 0; m < 4; m++)
#pragma unroll
      for (int n = 0; n < 4; n++) {
        acc[m][n] = __builtin_amdgcn_mfma_f32_16x16x32_bf16(af[0][m], bfr[0][n], acc[m][n], 0, 0, 0);
        acc[m][n] = __builtin_amdgcn_mfma_f32_16x16x32_bf16(af[1][m], bfr[1][n], acc[m][n], 0, 0, 0);
      }
    __syncthreads();  // all waves done reading before next overwrite
  }
  // epilogue: n outer so col-derived address math is hoisted
#pragma unroll
  for (int n = 0; n < 4; n++) {
    int col = bn * 128 + wn * 64 + n * 16 + lrow;
    float bv = (MODE & 1) ? bias[col] : 0.0f;
    if (MODE & 16) {
      // col factors as (h, hd, c) with c fastest; c=0:K, c=1:Q, c=2:V (all [bh][S][64])
      int c = col % 3;
      int hd = (col / 3) & 63;
      int h = col / 192;
      u16* dst = (c == 0) ? Kc : (c == 1) ? Qc : Vc;
#pragma unroll
      for (int m = 0; m < 4; m++)
#pragma unroll
        for (int r = 0; r < 4; r++) {
          int row = bm * 128 + wm * 64 + m * 16 + lgr * 4 + r;
          int bb = row >> 11, sIdx = row & 2047;
          dst[(((size_t)(bb * H_ + h)) * S_ + sIdx) * HD_ + hd] = f2bf(acc[m][n][r]);
        }
    } else {
#pragma unroll
      for (int m = 0; m < 4; m++)
#pragma unroll
        for (int r = 0; r < 4; r++) {
          int row = bm * 128 + wm * 64 + m * 16 + lgr * 4 + r;
          float v = acc[m][n][r] + bv;
          if (MODE & 2) v = gelu_f(v);
          if (MODE & 4) v += res[(size_t)row * N + col];
          if (MODE & 8) Cb[(size_t)row * N + col] = f2bf(v);
          else          Cf[(size_t)row * N + col] = v;
        }
    }
  }
}

// ---------------- causal flash attention, 32x32 swapped-QK^T, in-register softmax ---------
// Qc,Kc [bh][S][64] bf16, Vt [bh][64][S] bf16. One wave per 32 q rows. No LDS.
// S_tile = mfma(K, Q): col=lane&31=q, row=key=(reg&3)+8*(reg>>2)+4*hi.
// Per-lane softmax state (q = lane&31 for both halves; halves hold disjoint key sets).
// PV A-frag rebuilt in-register: swap32(cvtpk(p0,p1), cvtpk(p4,p5)) -> words 0,2 (T12).
template <int NSUB, bool MASK>
__device__ __forceinline__ void attn_chunk32(
    const u16* __restrict__ Kh, const u16* __restrict__ Vh,
    const bf16x8 (&qf)[4], f32x16 (&o)[2],
    float& mrun, float& lrun, int kb, int qrow, int hi, int ln31) {
  f32x16 s[NSUB];
#pragma unroll
  for (int sub = 0; sub < NSUB; sub++) {
    f32x16 z = zero16();
    __builtin_amdgcn_s_setprio(1);
#pragma unroll
    for (int ks = 0; ks < 4; ks++) {
      bf16x8 kfr = *(const bf16x8*)(Kh + (size_t)(kb + sub * 32 + ln31) * HD_ + ks * 16 + hi * 8);
      z = __builtin_amdgcn_mfma_f32_32x32x16_bf16(kfr, qf[ks], z, 0, 0, 0);
    }
    __builtin_amdgcn_s_setprio(0);
    s[sub] = z;
  }
  // mask + per-lane max on raw scores (SCALE>0 monotone)
  float pmax = -3.0e38f;
#pragma unroll
  for (int sub = 0; sub < NSUB; sub++)
#pragma unroll
    for (int r = 0; r < 16; r++) {
      if (MASK) {
        int key = kb + sub * 32 + (r & 3) + 8 * (r >> 2) + 4 * hi;
        if (key > qrow) s[sub][r] = -3.0e38f;
      }
      pmax = fmaxf(pmax, s[sub][r]);
    }
  pmax = fmaxf(pmax, __shfl_xor(pmax, 32));  // full row max (both halves agree)
  bool ok = (pmax * SCALE_ <= mrun + THR_);
  if (!__all(ok)) {
    float mnew = fmaxf(mrun, pmax * SCALE_);
    float corr = __builtin_amdgcn_exp2f(mrun - mnew);
    mrun = mnew;
    lrun *= corr;
#pragma unroll
    for (int r = 0; r < 16; r++) {
      float cr = __shfl(corr, ((r & 3) + 8 * (r >> 2)) + 4 * hi);
      o[0][r] *= cr;
      o[1][r] *= cr;
    }
  }
  float m = mrun;
  float lacc = 0.f;
#pragma unroll
  for (int sub = 0; sub < NSUB; sub++)
#pragma unroll
    for (int r = 0; r < 16; r++) {
      float p = __builtin_amdgcn_exp2f(__builtin_fmaf(s[sub][r], SCALE_, -m));
      s[sub][r] = p;
      lacc += p;
    }
  lrun += lacc;
  // PV: rebuild A-frags in-register, V direct from Vt
#pragma unroll
  for (int sub = 0; sub < NSUB; sub++) {
    u32 a0 = cvtpk_bf16(s[sub][0], s[sub][1]);
    u32 a1 = cvtpk_bf16(s[sub][2], s[sub][3]);
    u32 a2 = cvtpk_bf16(s[sub][4], s[sub][5]);
    u32 a3 = cvtpk_bf16(s[sub][6], s[sub][7]);
    swap32(a0, a2);
    swap32(a1, a3);
    u32 b0 = cvtpk_bf16(s[sub][8], s[sub][9]);
    u32 b1 = cvtpk_bf16(s[sub][10], s[sub][11]);
    u32 b2 = cvtpk_bf16(s[sub][12], s[sub][13]);
    u32 b3 = cvtpk_bf16(s[sub][14], s[sub][15]);
    swap32(b0, b2);
    swap32(b1, b3);
    u32x4 fa = {a0, a1, a2, a3};
    u32x4 fb = {b0, b1, b2, b3};
    bf16x8 pa = __builtin_bit_cast(bf16x8, fa);  // keys sub*32 + 0..15
    bf16x8 pb = __builtin_bit_cast(bf16x8, fb);  // keys sub*32 + 16..31
    __builtin_amdgcn_s_setprio(1);
#pragma unroll
    for (int ht = 0; ht < 2; ht++) {
      const u16* vb = Vh + (size_t)(ht * 32 + ln31) * S_ + kb + sub * 32 + hi * 8;
      bf16x8 v1 = *(const bf16x8*)(vb);
      bf16x8 v2 = *(const bf16x8*)(vb + 16);
      o[ht] = __builtin_amdgcn_mfma_f32_32x32x16_bf16(pa, v1, o[ht], 0, 0, 0);
      o[ht] = __builtin_amdgcn_mfma_f32_32x32x16_bf16(pb, v2, o[ht], 0, 0, 0);
    }
    __builtin_amdgcn_s_setprio(0);
  }
}

__global__ __launch_bounds__(64) void attn_kernel(const u16* __restrict__ Q,
                                                  const u16* __restrict__ Kk,
                                                  const u16* __restrict__ Vt,
                                                  u16* __restrict__ ctx) {
  int lane = threadIdx.x & 63;
  int strip = (S_ / 32) - 1 - (int)(blockIdx.x >> 6);  // heavy strips first
  int bh = blockIdx.x & 63;
  int b = bh >> 4, h = bh & 15;
  const u16* Qh = Q + (size_t)bh * S_ * HD_;
  const u16* Kh = Kk + (size_t)bh * S_ * HD_;
  const u16* Vh = Vt + (size_t)bh * HD_ * S_;
  int qbase = strip * 32;
  int ln31 = lane & 31, hi = lane >> 5;
  int qrow = qbase + ln31;

  // Q B-frags: lane holds q=ln31, k-slice ks*16 + hi*8 .. +7 (contiguous in Qc)
  bf16x8 qf[4];
#pragma unroll
  for (int ks = 0; ks < 4; ks++)
    qf[ks] = *(const bf16x8*)(Qh + (size_t)qrow * HD_ + ks * 16 + hi * 8);

  f32x16 o[2] = {zero16(), zero16()};
  float mrun = -1.0e30f, lrun = 0.f;

  int nf64 = qbase >> 6;
  for (int kt = 0; kt < nf64; kt++)
    attn_chunk32<2, false>(Kh, Vh, qf, o, mrun, lrun, kt * 64, qrow, hi, ln31);
  if (qbase & 32)
    attn_chunk32<1, false>(Kh, Vh, qf, o, mrun, lrun, qbase - 32, qrow, hi, ln31);
  attn_chunk32<1, true>(Kh, Vh, qf, o, mrun, lrun, qbase, qrow, hi, ln31);

  float l = lrun + __shfl_xor(lrun, 32);
  float inv = 1.0f / l;  // per-lane, q = ln31
#pragma unroll
  for (int r = 0; r < 16; r++) {
    float invr = __shfl(inv, ((r & 3) + 8 * (r >> 2)) + 4 * hi);
    int q = qbase + (r & 3) + 8 * (r >> 2) + 4 * hi;
    size_t base = ((size_t)b * S_ + q) * D_ + h * HD_;
    ctx[base + ln31] = f2bf(o[0][r] * invr);
    ctx[base + 32 + ln31] = f2bf(o[1][r] * invr);
  }
}

extern "C" void kernel_launch(void* const* d_in, const int* in_sizes, int n_in,
                              void* d_out, int out_size, void* d_ws, size_t ws_size,
                              hipStream_t stream) {
  const float* x = (const float*)d_in[0];
  const float* ln1w = (const float*)d_in[1];
  const float* ln1b = (const float*)d_in[2];
  const float* wqkv = (const float*)d_in[3];
  const float* wproj = (const float*)d_in[4];
  const float* bproj = (const float*)d_in[5];
  const float* ln2w = (const float*)d_in[6];
  const float* ln2b = (const float*)d_in[7];
  const float* wff1 = (const float*)d_in[8];
  const float* bff1 = (const float*)d_in[9];
  const float* wff2 = (const float*)d_in[10];
  const float* bff2 = (const float*)d_in[11];

  char* ws = (char*)d_ws;
  u16* wqkvT = (u16*)(ws + 0);                 //  6 MB  [3072][1024]
  u16* wprojT = (u16*)(ws + 6291456);          //  2 MB  [1024][1024]
  u16* wff1T = (u16*)(ws + 8388608);           //  8 MB  [4096][1024]
  u16* wff2T = (u16*)(ws + 16777216);          //  8 MB  [1024][4096]
  u16* h1 = (u16*)(ws + 25165824);             // 16 MB  [8192][1024]; dead after QKV gemm
  u16* Vt = (u16*)(ws + 25165824);             // 16 MB  [bh][64][S]; written after h1 dead
  u16* Qc = (u16*)(ws + 41943040);             // 16 MB  [bh][S][64]
  u16* Kc = (u16*)(ws + 58720256);             // 16 MB
  u16* Vc = (u16*)(ws + 75497472);             // 16 MB  [bh][S][64]
  u16* ctx = (u16*)(ws + 92274688);            // 16 MB  [8192][1024]
  float* x1 = (float*)(ws + 109051904);        // 32 MB  [8192][1024]
  u16* h2 = (u16*)(ws + 142606336);            // 16 MB
  u16* g = (u16*)(ws + 25165824);              // 64 MB  [8192][4096]; overlays h1/Vt/Qc/Kc/Vc
  float* outp = (float*)d_out;

  wconv_kernel<<<(1024 / 32) * (3072 / 32), 256, 0, stream>>>(wqkv, wqkvT, 1024, 3072);
  wconv_kernel<<<(1024 / 32) * (1024 / 32), 256, 0, stream>>>(wproj, wprojT, 1024, 1024);
  wconv_kernel<<<(1024 / 32) * (4096 / 32), 256, 0, stream>>>(wff1, wff1T, 1024, 4096);
  wconv_kernel<<<(4096 / 32) * (1024 / 32), 256, 0, stream>>>(wff2, wff2T, 4096, 1024);

  ln_kernel<<<8192, 256, 0, stream>>>(x, ln1w, ln1b, h1);
  gemm_kernel<16><<<64 * 24, 256, 0, stream>>>(h1, wqkvT, nullptr, nullptr, nullptr, nullptr,
                                               Qc, Kc, Vc, 8192, 3072, 1024);
  vtrans_kernel<<<64 * 32, 256, 0, stream>>>(Vc, Vt);
  attn_kernel<<<64 * (S_ / 32), 64, 0, stream>>>(Qc, Kc, Vt, ctx);
  gemm_kernel<5><<<64 * 8, 256, 0, stream>>>(ctx, wprojT, bproj, x, x1, nullptr,
                                             nullptr, nullptr, nullptr, 8192, 1024, 1024);
  ln_kernel<<<8192, 256, 0, stream>>>(x1, ln2w, ln2b, h2);
  gemm_kernel<11><<<64 * 32, 256, 0, stream>>>(h2, wff1T, bff1, nullptr, nullptr, g,
                                               nullptr, nullptr, nullptr, 8192, 4096, 1024);
  gemm_kernel<5><<<64 * 8, 256, 0, stream>>>(g, wff2T, bff2, x1, outp, nullptr,
                                             nullptr, nullptr, nullptr, 8192, 1024, 4096);
}

// Round 7
// 472.310 us; speedup vs baseline: 1.0784x; 1.0330x over previous
//
#include <hip/hip_runtime.h>

typedef unsigned short u16;
typedef unsigned int u32;
typedef __bf16 bf16x8 __attribute__((ext_vector_type(8)));
typedef float f32x4 __attribute__((ext_vector_type(4)));
typedef float f32x16 __attribute__((ext_vector_type(16)));
typedef unsigned short us8 __attribute__((ext_vector_type(8)));
typedef unsigned short us4 __attribute__((ext_vector_type(4)));
typedef unsigned int u32x4 __attribute__((ext_vector_type(4)));

#define B_ 4
#define S_ 2048
#define D_ 1024
#define H_ 16
#define HD_ 64
#define EPS_ 1e-5f
#define SCALE_ (0.125f * 1.44269504088896341f)  // HD^-0.5 * log2(e); exp via exp2
#define THR_ 3.0f                               // defer-max threshold (log2 domain)

__device__ __forceinline__ u16 f2bf(float f) {
  unsigned u = __builtin_bit_cast(unsigned, f);
  u = (u + 0x7FFFu + ((u >> 16) & 1u)) >> 16;
  return (u16)u;
}

// tanh-form GELU via exp2: x - x/(1+t), t=exp2(c1*(x+c2*x^3)); |err| vs erf-GELU < 1e-3
__device__ __forceinline__ float gelu_f(float x) {
  float u = x * (2.3022388f + 0.10294971f * x * x);
  float te = __builtin_amdgcn_exp2f(u);
  return x - x * __builtin_amdgcn_rcpf(1.0f + te);
}

typedef const __attribute__((address_space(1))) unsigned int* gp1;
typedef __attribute__((address_space(3))) unsigned int* lp3;
__device__ __forceinline__ void gl_lds16(const void* g, void* l) {
  __builtin_amdgcn_global_load_lds((gp1)(unsigned long long)g,
                                   (lp3)(unsigned int)(unsigned long long)l,
                                   16, 0, 0);
}

__device__ __forceinline__ u32 cvtpk_bf16(float lo, float hi) {
  u32 d;
  asm("v_cvt_pk_bf16_f32 %0, %1, %2" : "=v"(d) : "v"(lo), "v"(hi));
  return d;
}
// swaps a's lanes 32-63 with b's lanes 0-31: a' = [a.lo | b.lo], b' = [a.hi | b.hi]
__device__ __forceinline__ void swap32(u32& a, u32& b) {
  asm("v_permlane32_swap_b32 %0, %1" : "+v"(a), "+v"(b));
}

__device__ __forceinline__ f32x16 zero16() {
  f32x16 z;
#pragma unroll
  for (int i = 0; i < 16; i++) z[i] = 0.f;
  return z;
}

// ---------------- weight transpose + f32->bf16 convert: W[K][N] -> Wt[N][K] ----------------
__global__ __launch_bounds__(256) void wconv_kernel(const float* __restrict__ W,
                                                    u16* __restrict__ Wt,
                                                    int Kd, int N) {
  __shared__ u16 tile[32][33];
  int bid = blockIdx.x;
  int nbn = N >> 5;
  int tk = bid / nbn, tn = bid % nbn;
  int tx = threadIdx.x & 31, ty = threadIdx.x >> 5;
#pragma unroll
  for (int i = 0; i < 4; i++) {
    int r = ty + i * 8;
    tile[r][tx] = f2bf(W[(size_t)(tk * 32 + r) * N + tn * 32 + tx]);
  }
  __syncthreads();
#pragma unroll
  for (int i = 0; i < 4; i++) {
    int r = ty + i * 8;
    Wt[(size_t)(tn * 32 + r) * Kd + tk * 32 + tx] = tile[tx][r];
  }
}

// ---------------- V transpose: Vc [bh][S][64] -> Vt [bh][64][S] ----------------------------
__global__ __launch_bounds__(256) void vtrans_kernel(const u16* __restrict__ Vc,
                                                     u16* __restrict__ Vt) {
  __shared__ u16 tile[64][72];
  int bh = blockIdx.x >> 5;
  int sb = blockIdx.x & 31;
  const u16* src = Vc + ((size_t)bh * S_ + sb * 64) * HD_;
  int r = threadIdx.x >> 2, c0 = (threadIdx.x & 3) * 16;
  *(us8*)&tile[r][c0] = *(const us8*)(src + r * HD_ + c0);
  *(us8*)&tile[r][c0 + 8] = *(const us8*)(src + r * HD_ + c0 + 8);
  __syncthreads();
  u16* dst = Vt + (size_t)bh * HD_ * S_ + sb * 64;
  int hd = threadIdx.x >> 2;
  int s0 = (threadIdx.x & 3) * 16;
  us8 a, b;
#pragma unroll
  for (int j = 0; j < 8; j++) a[j] = tile[s0 + j][hd];
#pragma unroll
  for (int j = 0; j < 8; j++) b[j] = tile[s0 + 8 + j][hd];
  *(us8*)(dst + (size_t)hd * S_ + s0) = a;
  *(us8*)(dst + (size_t)hd * S_ + s0 + 8) = b;
}

// ---------------- LayerNorm: f32 in -> bf16 out, one block per row (D=1024) ----------------
__global__ __launch_bounds__(256) void ln_kernel(const float* __restrict__ x,
                                                 const float* __restrict__ w,
                                                 const float* __restrict__ b,
                                                 u16* __restrict__ out) {
  int row = blockIdx.x;
  int t = threadIdx.x;
  int lane = t & 63, wid = t >> 6;
  const float4* xr = (const float4*)(x + (size_t)row * D_);
  float4 v = xr[t];
  float s = v.x + v.y + v.z + v.w;
  float q = v.x * v.x + v.y * v.y + v.z * v.z + v.w * v.w;
#pragma unroll
  for (int off = 1; off < 64; off <<= 1) {
    s += __shfl_xor(s, off);
    q += __shfl_xor(q, off);
  }
  __shared__ float red[8];
  if (lane == 0) { red[wid] = s; red[4 + wid] = q; }
  __syncthreads();
  s = red[0] + red[1] + red[2] + red[3];
  q = red[4] + red[5] + red[6] + red[7];
  float mu = s * (1.0f / D_);
  float var = q * (1.0f / D_) - mu * mu;
  float rs = rsqrtf(var + EPS_);
  int c = t * 4;
  float4 wv = *(const float4*)(w + c);
  float4 bv = *(const float4*)(b + c);
  us4 o;
  o[0] = f2bf((v.x - mu) * rs * wv.x + bv.x);
  o[1] = f2bf((v.y - mu) * rs * wv.y + bv.y);
  o[2] = f2bf((v.z - mu) * rs * wv.z + bv.z);
  o[3] = f2bf((v.w - mu) * rs * wv.w + bv.w);
  *(us4*)(out + (size_t)row * D_ + c) = o;
}

// ---------------- GEMM 256-wide: 8 waves (2Mx4N), BK=64, LDS dbuf, counted vmcnt -----------
// C = A[M,K] * Bt[N,K]^T. T2 XOR swizzle (pre-swizzled global src, linear LDS dest).
// Per K-tile: issue next tile's stage rounds, vmcnt(RR) [current landed, next in flight],
// raw s_barrier, 4 quadrant MFMA clusters, raw s_barrier. Never vmcnt(0) mid-loop.
// MODE bits: 1=bias, 2=gelu, 4=residual(f32), 8=bf16 out, 16=QKV interleaved split store
template <int MODE, int BM>
__global__ __launch_bounds__(512) void gemm256_kernel(
    const u16* __restrict__ A, const u16* __restrict__ Bt,
    const float* __restrict__ bias, const float* __restrict__ res,
    float* __restrict__ Cf, u16* __restrict__ Cb,
    u16* __restrict__ Qc, u16* __restrict__ Kc, u16* __restrict__ Vc,
    int M, int N, int K) {
  constexpr int MFRAG = BM / 32;   // per-wave m-frags (8 for BM=256, 4 for BM=128)
  constexpr int MH = MFRAG / 2;
  constexpr int AR = BM / 64;      // A stage rounds per K-tile
  constexpr int RR = AR + 4;       // total stage rounds (gl_lds instrs) per K-tile
  extern __shared__ __align__(16) u16 sm[];
  u16* Al = sm;                    // [2][BM*64]
  u16* Bl = sm + 2 * BM * 64;      // [2][256*64]
  int t = threadIdx.x;
  int nbn = N >> 8;
  int nwg = gridDim.x;
  int cpx = nwg >> 3;
  int bid = (blockIdx.x % 8) * cpx + blockIdx.x / 8;  // XCD swizzle (grids %8==0)
  int bm = bid / nbn, bn = bid % nbn;
  int lane = t & 63, wid = t >> 6;
  int wm = wid >> 2, wn = wid & 3;               // 2 x 4 wave grid
  int lrow = lane & 15, lgr = lane >> 4;
  int sl7 = lrow & 7;
  const u16* Ab = A + (size_t)bm * BM * K;
  const u16* Bb = Bt + (size_t)bn * 256 * K;
  // staging: round = one gl_lds by all 8 waves = 64 rows x 64 cols. thread t ->
  // row (t>>3) in round, src col slot (t&7)^(row&7); LDS dest linear = +8*t elems.
  int srt = t >> 3;
  int ssc = (((t & 7) ^ (srt & 7)) << 3);
  const u16* Asrc = Ab + (size_t)srt * K + ssc;
  const u16* Bsrc = Bb + (size_t)srt * K + ssc;

  auto stage = [&](int kt, int bsel) {
    int k0 = kt * 64;
    u16* Ad = Al + bsel * (BM * 64) + t * 8;
    u16* Bd = Bl + bsel * (256 * 64) + t * 8;
#pragma unroll
    for (int a2 = 0; a2 < AR; a2++)
      gl_lds16(Asrc + (size_t)(a2 * 64) * K + k0, Ad + a2 * 4096);
#pragma unroll
    for (int b2 = 0; b2 < 4; b2++)
      gl_lds16(Bsrc + (size_t)(b2 * 64) * K + k0, Bd + b2 * 4096);
  };

  f32x4 acc[MFRAG][4] = {};
  int NT = K >> 6;
  stage(0, 0);
  for (int kt = 0; kt < NT; kt++) {
    int cur = kt & 1;
    if (kt + 1 < NT) {
      stage(kt + 1, cur ^ 1);  // into buffer whose readers finished last iter
      if constexpr (RR == 8) asm volatile("s_waitcnt vmcnt(8)" ::: "memory");
      else                   asm volatile("s_waitcnt vmcnt(6)" ::: "memory");
    } else {
      asm volatile("s_waitcnt vmcnt(0)" ::: "memory");
    }
    __builtin_amdgcn_sched_barrier(0);
    __builtin_amdgcn_s_barrier();  // all waves' tile-kt stages landed
    __builtin_amdgcn_sched_barrier(0);
    const u16* Ac = Al + cur * (BM * 64);
    const u16* Bc = Bl + cur * (256 * 64);
#pragma unroll
    for (int mq = 0; mq < 2; mq++) {
      bf16x8 af[2][MH];
#pragma unroll
      for (int ks = 0; ks < 2; ks++) {
        int slot = ((ks << 2) | lgr) ^ sl7;
#pragma unroll
        for (int mm = 0; mm < MH; mm++)
          af[ks][mm] = *(const bf16x8*)&Ac[(wm * (BM / 2) + (mq * MH + mm) * 16 + lrow) * 64 + slot * 8];
      }
#pragma unroll
      for (int nq = 0; nq < 2; nq++) {
        bf16x8 bfm[2][2];
#pragma unroll
        for (int ks = 0; ks < 2; ks++) {
          int slot = ((ks << 2) | lgr) ^ sl7;
#pragma unroll
          for (int nn = 0; nn < 2; nn++)
            bfm[ks][nn] = *(const bf16x8*)&Bc[(wn * 64 + (nq * 2 + nn) * 16 + lrow) * 64 + slot * 8];
        }
        __builtin_amdgcn_s_setprio(1);
#pragma unroll
        for (int mm = 0; mm < MH; mm++)
#pragma unroll
          for (int nn = 0; nn < 2; nn++) {
            int m = mq * MH + mm, n = nq * 2 + nn;
            acc[m][n] = __builtin_amdgcn_mfma_f32_16x16x32_bf16(af[0][mm], bfm[0][nn], acc[m][n], 0, 0, 0);
            acc[m][n] = __builtin_amdgcn_mfma_f32_16x16x32_bf16(af[1][mm], bfm[1][nn], acc[m][n], 0, 0, 0);
          }
        __builtin_amdgcn_s_setprio(0);
      }
    }
    __builtin_amdgcn_sched_barrier(0);
    __builtin_amdgcn_s_barrier();  // all waves done reading buf[cur]
    __builtin_amdgcn_sched_barrier(0);
  }
  // epilogue: n outer so col-derived address math is hoisted
#pragma unroll
  for (int n = 0; n < 4; n++) {
    int col = bn * 256 + wn * 64 + n * 16 + lrow;
    float bv = (MODE & 1) ? bias[col] : 0.0f;
    if (MODE & 16) {
      // col factors as (h, hd, c) with c fastest; c=0:K, c=1:Q, c=2:V (all [bh][S][64])
      int c = col % 3;
      int hd = (col / 3) & 63;
      int h = col / 192;
      u16* dst = (c == 0) ? Kc : (c == 1) ? Qc : Vc;
#pragma unroll
      for (int m = 0; m < MFRAG; m++)
#pragma unroll
        for (int r = 0; r < 4; r++) {
          int row = bm * BM + wm * (BM / 2) + m * 16 + lgr * 4 + r;
          int bb = row >> 11, sIdx = row & 2047;
          dst[(((size_t)(bb * H_ + h)) * S_ + sIdx) * HD_ + hd] = f2bf(acc[m][n][r]);
        }
    } else {
#pragma unroll
      for (int m = 0; m < MFRAG; m++)
#pragma unroll
        for (int r = 0; r < 4; r++) {
          int row = bm * BM + wm * (BM / 2) + m * 16 + lgr * 4 + r;
          float v = acc[m][n][r] + bv;
          if (MODE & 2) v = gelu_f(v);
          if (MODE & 4) v += res[(size_t)row * N + col];
          if (MODE & 8) Cb[(size_t)row * N + col] = f2bf(v);
          else          Cf[(size_t)row * N + col] = v;
        }
    }
  }
}

// ---------------- causal flash attention, 32x32 swapped-QK^T, in-register softmax ---------
// Qc,Kc [bh][S][64] bf16, Vt [bh][64][S] bf16. One wave per 32 q rows. No LDS.
// S_tile = mfma(K, Q): col=lane&31=q, row=key=(reg&3)+8*(reg>>2)+4*hi.
template <int NSUB, bool MASK>
__device__ __forceinline__ void attn_chunk32(
    const u16* __restrict__ Kh, const u16* __restrict__ Vh,
    const bf16x8 (&qf)[4], f32x16 (&o)[2],
    float& mrun, float& lrun, int kb, int qrow, int hi, int ln31) {
  f32x16 s[NSUB];
#pragma unroll
  for (int sub = 0; sub < NSUB; sub++) {
    f32x16 z = zero16();
    __builtin_amdgcn_s_setprio(1);
#pragma unroll
    for (int ks = 0; ks < 4; ks++) {
      bf16x8 kfr = *(const bf16x8*)(Kh + (size_t)(kb + sub * 32 + ln31) * HD_ + ks * 16 + hi * 8);
      z = __builtin_amdgcn_mfma_f32_32x32x16_bf16(kfr, qf[ks], z, 0, 0, 0);
    }
    __builtin_amdgcn_s_setprio(0);
    s[sub] = z;
  }
  float pmax = -3.0e38f;
#pragma unroll
  for (int sub = 0; sub < NSUB; sub++)
#pragma unroll
    for (int r = 0; r < 16; r++) {
      if (MASK) {
        int key = kb + sub * 32 + (r & 3) + 8 * (r >> 2) + 4 * hi;
        if (key > qrow) s[sub][r] = -3.0e38f;
      }
      pmax = fmaxf(pmax, s[sub][r]);
    }
  pmax = fmaxf(pmax, __shfl_xor(pmax, 32));
  bool ok = (pmax * SCALE_ <= mrun + THR_);
  if (!__all(ok)) {
    float mnew = fmaxf(mrun, pmax * SCALE_);
    float corr = __builtin_amdgcn_exp2f(mrun - mnew);
    mrun = mnew;
    lrun *= corr;
#pragma unroll
    for (int r = 0; r < 16; r++) {
      float cr = __shfl(corr, ((r & 3) + 8 * (r >> 2)) + 4 * hi);
      o[0][r] *= cr;
      o[1][r] *= cr;
    }
  }
  float m = mrun;
  float lacc = 0.f;
#pragma unroll
  for (int sub = 0; sub < NSUB; sub++)
#pragma unroll
    for (int r = 0; r < 16; r++) {
      float p = __builtin_amdgcn_exp2f(__builtin_fmaf(s[sub][r], SCALE_, -m));
      s[sub][r] = p;
      lacc += p;
    }
  lrun += lacc;
#pragma unroll
  for (int sub = 0; sub < NSUB; sub++) {
    u32 a0 = cvtpk_bf16(s[sub][0], s[sub][1]);
    u32 a1 = cvtpk_bf16(s[sub][2], s[sub][3]);
    u32 a2 = cvtpk_bf16(s[sub][4], s[sub][5]);
    u32 a3 = cvtpk_bf16(s[sub][6], s[sub][7]);
    swap32(a0, a2);
    swap32(a1, a3);
    u32 b0 = cvtpk_bf16(s[sub][8], s[sub][9]);
    u32 b1 = cvtpk_bf16(s[sub][10], s[sub][11]);
    u32 b2 = cvtpk_bf16(s[sub][12], s[sub][13]);
    u32 b3 = cvtpk_bf16(s[sub][14], s[sub][15]);
    swap32(b0, b2);
    swap32(b1, b3);
    u32x4 fa = {a0, a1, a2, a3};
    u32x4 fb = {b0, b1, b2, b3};
    bf16x8 pa = __builtin_bit_cast(bf16x8, fa);
    bf16x8 pb = __builtin_bit_cast(bf16x8, fb);
    __builtin_amdgcn_s_setprio(1);
#pragma unroll
    for (int ht = 0; ht < 2; ht++) {
      const u16* vb = Vh + (size_t)(ht * 32 + ln31) * S_ + kb + sub * 32 + hi * 8;
      bf16x8 v1 = *(const bf16x8*)(vb);
      bf16x8 v2 = *(const bf16x8*)(vb + 16);
      o[ht] = __builtin_amdgcn_mfma_f32_32x32x16_bf16(pa, v1, o[ht], 0, 0, 0);
      o[ht] = __builtin_amdgcn_mfma_f32_32x32x16_bf16(pb, v2, o[ht], 0, 0, 0);
    }
    __builtin_amdgcn_s_setprio(0);
  }
}

__global__ __launch_bounds__(64) void attn_kernel(const u16* __restrict__ Q,
                                                  const u16* __restrict__ Kk,
                                                  const u16* __restrict__ Vt,
                                                  u16* __restrict__ ctx) {
  int lane = threadIdx.x & 63;
  int strip = (S_ / 32) - 1 - (int)(blockIdx.x >> 6);  // heavy strips first
  int bh = blockIdx.x & 63;
  int b = bh >> 4, h = bh & 15;
  const u16* Qh = Q + (size_t)bh * S_ * HD_;
  const u16* Kh = Kk + (size_t)bh * S_ * HD_;
  const u16* Vh = Vt + (size_t)bh * HD_ * S_;
  int qbase = strip * 32;
  int ln31 = lane & 31, hi = lane >> 5;
  int qrow = qbase + ln31;

  bf16x8 qf[4];
#pragma unroll
  for (int ks = 0; ks < 4; ks++)
    qf[ks] = *(const bf16x8*)(Qh + (size_t)qrow * HD_ + ks * 16 + hi * 8);

  f32x16 o[2] = {zero16(), zero16()};
  float mrun = -1.0e30f, lrun = 0.f;

  int nf64 = qbase >> 6;
  for (int kt = 0; kt < nf64; kt++)
    attn_chunk32<2, false>(Kh, Vh, qf, o, mrun, lrun, kt * 64, qrow, hi, ln31);
  if (qbase & 32)
    attn_chunk32<1, false>(Kh, Vh, qf, o, mrun, lrun, qbase - 32, qrow, hi, ln31);
  attn_chunk32<1, true>(Kh, Vh, qf, o, mrun, lrun, qbase, qrow, hi, ln31);

  float l = lrun + __shfl_xor(lrun, 32);
  float inv = 1.0f / l;
#pragma unroll
  for (int r = 0; r < 16; r++) {
    float invr = __shfl(inv, ((r & 3) + 8 * (r >> 2)) + 4 * hi);
    int q = qbase + (r & 3) + 8 * (r >> 2) + 4 * hi;
    size_t base = ((size_t)b * S_ + q) * D_ + h * HD_;
    ctx[base + ln31] = f2bf(o[0][r] * invr);
    ctx[base + 32 + ln31] = f2bf(o[1][r] * invr);
  }
}

extern "C" void kernel_launch(void* const* d_in, const int* in_sizes, int n_in,
                              void* d_out, int out_size, void* d_ws, size_t ws_size,
                              hipStream_t stream) {
  const float* x = (const float*)d_in[0];
  const float* ln1w = (const float*)d_in[1];
  const float* ln1b = (const float*)d_in[2];
  const float* wqkv = (const float*)d_in[3];
  const float* wproj = (const float*)d_in[4];
  const float* bproj = (const float*)d_in[5];
  const float* ln2w = (const float*)d_in[6];
  const float* ln2b = (const float*)d_in[7];
  const float* wff1 = (const float*)d_in[8];
  const float* bff1 = (const float*)d_in[9];
  const float* wff2 = (const float*)d_in[10];
  const float* bff2 = (const float*)d_in[11];

  char* ws = (char*)d_ws;
  u16* wqkvT = (u16*)(ws + 0);                 //  6 MB  [3072][1024]
  u16* wprojT = (u16*)(ws + 6291456);          //  2 MB  [1024][1024]
  u16* wff1T = (u16*)(ws + 8388608);           //  8 MB  [4096][1024]
  u16* wff2T = (u16*)(ws + 16777216);          //  8 MB  [1024][4096]
  u16* h1 = (u16*)(ws + 25165824);             // 16 MB  [8192][1024]; dead after QKV gemm
  u16* Vt = (u16*)(ws + 25165824);             // 16 MB  [bh][64][S]; written after h1 dead
  u16* Qc = (u16*)(ws + 41943040);             // 16 MB  [bh][S][64]
  u16* Kc = (u16*)(ws + 58720256);             // 16 MB
  u16* Vc = (u16*)(ws + 75497472);             // 16 MB  [bh][S][64]
  u16* ctx = (u16*)(ws + 92274688);            // 16 MB  [8192][1024]
  float* x1 = (float*)(ws + 109051904);        // 32 MB  [8192][1024]
  u16* h2 = (u16*)(ws + 142606336);            // 16 MB
  u16* g = (u16*)(ws + 25165824);              // 64 MB  [8192][4096]; overlays h1/Vt/Qc/Kc/Vc
  float* outp = (float*)d_out;

  // allow >64KB dynamic LDS for the 256-wide GEMMs (host-side attr, graph-capture safe)
  hipFuncSetAttribute((const void*)gemm256_kernel<16, 256>,
                      hipFuncAttributeMaxDynamicSharedMemorySize, 131072);
  hipFuncSetAttribute((const void*)gemm256_kernel<11, 256>,
                      hipFuncAttributeMaxDynamicSharedMemorySize, 131072);
  hipFuncSetAttribute((const void*)gemm256_kernel<5, 128>,
                      hipFuncAttributeMaxDynamicSharedMemorySize, 98304);

  wconv_kernel<<<(1024 / 32) * (3072 / 32), 256, 0, stream>>>(wqkv, wqkvT, 1024, 3072);
  wconv_kernel<<<(1024 / 32) * (1024 / 32), 256, 0, stream>>>(wproj, wprojT, 1024, 1024);
  wconv_kernel<<<(1024 / 32) * (4096 / 32), 256, 0, stream>>>(wff1, wff1T, 1024, 4096);
  wconv_kernel<<<(4096 / 32) * (1024 / 32), 256, 0, stream>>>(wff2, wff2T, 4096, 1024);

  ln_kernel<<<8192, 256, 0, stream>>>(x, ln1w, ln1b, h1);
  // QKV: 256x256 tiles, grid 32*12=384 (%8==0)
  gemm256_kernel<16, 256><<<384, 512, 131072, stream>>>(h1, wqkvT, nullptr, nullptr,
                                                        nullptr, nullptr, Qc, Kc, Vc,
                                                        8192, 3072, 1024);
  vtrans_kernel<<<64 * 32, 256, 0, stream>>>(Vc, Vt);
  attn_kernel<<<64 * (S_ / 32), 64, 0, stream>>>(Qc, Kc, Vt, ctx);
  // proj: 128x256 tiles, grid 64*4=256
  gemm256_kernel<5, 128><<<256, 512, 98304, stream>>>(ctx, wprojT, bproj, x, x1, nullptr,
                                                      nullptr, nullptr, nullptr,
                                                      8192, 1024, 1024);
  ln_kernel<<<8192, 256, 0, stream>>>(x1, ln2w, ln2b, h2);
  // FF1: 256x256 tiles, grid 32*16=512
  gemm256_kernel<11, 256><<<512, 512, 131072, stream>>>(h2, wff1T, bff1, nullptr, nullptr, g,
                                                        nullptr, nullptr, nullptr,
                                                        8192, 4096, 1024);
  // FF2: 128x256 tiles, grid 64*4=256 (K=4096)
  gemm256_kernel<5, 128><<<256, 512, 98304, stream>>>(g, wff2T, bff2, x1, outp, nullptr,
                                                      nullptr, nullptr, nullptr,
                                                      8192, 1024, 4096);
}

// Round 8
// 402.571 us; speedup vs baseline: 1.2652x; 1.1732x over previous
//
#include <hip/hip_runtime.h>

typedef unsigned short u16;
typedef unsigned int u32;
typedef __bf16 bf16x8 __attribute__((ext_vector_type(8)));
typedef float f32x4 __attribute__((ext_vector_type(4)));
typedef float f32x16 __attribute__((ext_vector_type(16)));
typedef unsigned short us8 __attribute__((ext_vector_type(8)));
typedef unsigned short us4 __attribute__((ext_vector_type(4)));
typedef unsigned int u32x4 __attribute__((ext_vector_type(4)));

#define B_ 4
#define S_ 2048
#define D_ 1024
#define H_ 16
#define HD_ 64
#define EPS_ 1e-5f
#define SCALE_ (0.125f * 1.44269504088896341f)  // HD^-0.5 * log2(e); exp via exp2
#define THR_ 3.0f                               // defer-max threshold (log2 domain)

__device__ __forceinline__ u16 f2bf(float f) {
  unsigned u = __builtin_bit_cast(unsigned, f);
  u = (u + 0x7FFFu + ((u >> 16) & 1u)) >> 16;
  return (u16)u;
}

// tanh-form GELU via exp2: x - x/(1+t), t=exp2(c1*(x+c2*x^3)); |err| vs erf-GELU < 1e-3
__device__ __forceinline__ float gelu_f(float x) {
  float u = x * (2.3022388f + 0.10294971f * x * x);
  float te = __builtin_amdgcn_exp2f(u);
  return x - x * __builtin_amdgcn_rcpf(1.0f + te);
}

typedef const __attribute__((address_space(1))) unsigned int* gp1;
typedef __attribute__((address_space(3))) unsigned int* lp3;
__device__ __forceinline__ void gl_lds16(const void* g, void* l) {
  __builtin_amdgcn_global_load_lds((gp1)(unsigned long long)g,
                                   (lp3)(unsigned int)(unsigned long long)l,
                                   16, 0, 0);
}

__device__ __forceinline__ u32 cvtpk_bf16(float lo, float hi) {
  u32 d;
  asm("v_cvt_pk_bf16_f32 %0, %1, %2" : "=v"(d) : "v"(lo), "v"(hi));
  return d;
}
// swaps a's lanes 32-63 with b's lanes 0-31
__device__ __forceinline__ void swap32(u32& a, u32& b) {
  asm("v_permlane32_swap_b32 %0, %1" : "+v"(a), "+v"(b));
}

__device__ __forceinline__ f32x16 zero16() {
  f32x16 z;
#pragma unroll
  for (int i = 0; i < 16; i++) z[i] = 0.f;
  return z;
}

// ---------------- weight transpose + f32->bf16 convert: W[K][N] -> Wt[N][K] ----------------
__global__ __launch_bounds__(256) void wconv_kernel(const float* __restrict__ W,
                                                    u16* __restrict__ Wt,
                                                    int Kd, int N) {
  __shared__ u16 tile[32][33];
  int bid = blockIdx.x;
  int nbn = N >> 5;
  int tk = bid / nbn, tn = bid % nbn;
  int tx = threadIdx.x & 31, ty = threadIdx.x >> 5;
#pragma unroll
  for (int i = 0; i < 4; i++) {
    int r = ty + i * 8;
    tile[r][tx] = f2bf(W[(size_t)(tk * 32 + r) * N + tn * 32 + tx]);
  }
  __syncthreads();
#pragma unroll
  for (int i = 0; i < 4; i++) {
    int r = ty + i * 8;
    Wt[(size_t)(tn * 32 + r) * Kd + tk * 32 + tx] = tile[tx][r];
  }
}

// ---------------- V transpose: Vc [bh][S][64] -> Vt [bh][64][S] ----------------------------
__global__ __launch_bounds__(256) void vtrans_kernel(const u16* __restrict__ Vc,
                                                     u16* __restrict__ Vt) {
  __shared__ u16 tile[64][72];
  int bh = blockIdx.x >> 5;
  int sb = blockIdx.x & 31;
  const u16* src = Vc + ((size_t)bh * S_ + sb * 64) * HD_;
  int r = threadIdx.x >> 2, c0 = (threadIdx.x & 3) * 16;
  *(us8*)&tile[r][c0] = *(const us8*)(src + r * HD_ + c0);
  *(us8*)&tile[r][c0 + 8] = *(const us8*)(src + r * HD_ + c0 + 8);
  __syncthreads();
  u16* dst = Vt + (size_t)bh * HD_ * S_ + sb * 64;
  int hd = threadIdx.x >> 2;
  int s0 = (threadIdx.x & 3) * 16;
  us8 a, b;
#pragma unroll
  for (int j = 0; j < 8; j++) a[j] = tile[s0 + j][hd];
#pragma unroll
  for (int j = 0; j < 8; j++) b[j] = tile[s0 + 8 + j][hd];
  *(us8*)(dst + (size_t)hd * S_ + s0) = a;
  *(us8*)(dst + (size_t)hd * S_ + s0 + 8) = b;
}

// ---------------- LayerNorm: f32 in -> bf16 out, one block per row (D=1024) ----------------
__global__ __launch_bounds__(256) void ln_kernel(const float* __restrict__ x,
                                                 const float* __restrict__ w,
                                                 const float* __restrict__ b,
                                                 u16* __restrict__ out) {
  int row = blockIdx.x;
  int t = threadIdx.x;
  int lane = t & 63, wid = t >> 6;
  const float4* xr = (const float4*)(x + (size_t)row * D_);
  float4 v = xr[t];
  float s = v.x + v.y + v.z + v.w;
  float q = v.x * v.x + v.y * v.y + v.z * v.z + v.w * v.w;
#pragma unroll
  for (int off = 1; off < 64; off <<= 1) {
    s += __shfl_xor(s, off);
    q += __shfl_xor(q, off);
  }
  __shared__ float red[8];
  if (lane == 0) { red[wid] = s; red[4 + wid] = q; }
  __syncthreads();
  s = red[0] + red[1] + red[2] + red[3];
  q = red[4] + red[5] + red[6] + red[7];
  float mu = s * (1.0f / D_);
  float var = q * (1.0f / D_) - mu * mu;
  float rs = rsqrtf(var + EPS_);
  int c = t * 4;
  float4 wv = *(const float4*)(w + c);
  float4 bv = *(const float4*)(b + c);
  us4 o;
  o[0] = f2bf((v.x - mu) * rs * wv.x + bv.x);
  o[1] = f2bf((v.y - mu) * rs * wv.y + bv.y);
  o[2] = f2bf((v.z - mu) * rs * wv.z + bv.z);
  o[3] = f2bf((v.w - mu) * rs * wv.w + bv.w);
  *(us4*)(out + (size_t)row * D_ + c) = o;
}

// ---------------- GEMM 256-wide: 8 waves (2Mx4N), BK=64, LDS dbuf, counted vmcnt -----------
// MODE bits: 1=bias, 2=gelu, 4=residual(f32), 8=bf16 out, 16=QKV interleaved split store
template <int MODE, int BM>
__global__ __launch_bounds__(512) void gemm256_kernel(
    const u16* __restrict__ A, const u16* __restrict__ Bt,
    const float* __restrict__ bias, const float* __restrict__ res,
    float* __restrict__ Cf, u16* __restrict__ Cb,
    u16* __restrict__ Qc, u16* __restrict__ Kc, u16* __restrict__ Vc,
    int M, int N, int K) {
  constexpr int MFRAG = BM / 32;
  constexpr int MH = MFRAG / 2;
  constexpr int AR = BM / 64;
  constexpr int RR = AR + 4;
  extern __shared__ __align__(16) u16 sm[];
  u16* Al = sm;
  u16* Bl = sm + 2 * BM * 64;
  int t = threadIdx.x;
  int nbn = N >> 8;
  int nwg = gridDim.x;
  int cpx = nwg >> 3;
  int bid = (blockIdx.x % 8) * cpx + blockIdx.x / 8;
  int bm = bid / nbn, bn = bid % nbn;
  int lane = t & 63, wid = t >> 6;
  int wm = wid >> 2, wn = wid & 3;
  int lrow = lane & 15, lgr = lane >> 4;
  int sl7 = lrow & 7;
  const u16* Ab = A + (size_t)bm * BM * K;
  const u16* Bb = Bt + (size_t)bn * 256 * K;
  int srt = t >> 3;
  int ssc = (((t & 7) ^ (srt & 7)) << 3);
  const u16* Asrc = Ab + (size_t)srt * K + ssc;
  const u16* Bsrc = Bb + (size_t)srt * K + ssc;

  auto stage = [&](int kt, int bsel) {
    int k0 = kt * 64;
    u16* Ad = Al + bsel * (BM * 64) + t * 8;
    u16* Bd = Bl + bsel * (256 * 64) + t * 8;
#pragma unroll
    for (int a2 = 0; a2 < AR; a2++)
      gl_lds16(Asrc + (size_t)(a2 * 64) * K + k0, Ad + a2 * 4096);
#pragma unroll
    for (int b2 = 0; b2 < 4; b2++)
      gl_lds16(Bsrc + (size_t)(b2 * 64) * K + k0, Bd + b2 * 4096);
  };

  f32x4 acc[MFRAG][4] = {};
  int NT = K >> 6;
  stage(0, 0);
  for (int kt = 0; kt < NT; kt++) {
    int cur = kt & 1;
    if (kt + 1 < NT) {
      stage(kt + 1, cur ^ 1);
      if constexpr (RR == 8) asm volatile("s_waitcnt vmcnt(8)" ::: "memory");
      else                   asm volatile("s_waitcnt vmcnt(6)" ::: "memory");
    } else {
      asm volatile("s_waitcnt vmcnt(0)" ::: "memory");
    }
    __builtin_amdgcn_sched_barrier(0);
    __builtin_amdgcn_s_barrier();
    __builtin_amdgcn_sched_barrier(0);
    const u16* Ac = Al + cur * (BM * 64);
    const u16* Bc = Bl + cur * (256 * 64);
#pragma unroll
    for (int mq = 0; mq < 2; mq++) {
      bf16x8 af[2][MH];
#pragma unroll
      for (int ks = 0; ks < 2; ks++) {
        int slot = ((ks << 2) | lgr) ^ sl7;
#pragma unroll
        for (int mm = 0; mm < MH; mm++)
          af[ks][mm] = *(const bf16x8*)&Ac[(wm * (BM / 2) + (mq * MH + mm) * 16 + lrow) * 64 + slot * 8];
      }
#pragma unroll
      for (int nq = 0; nq < 2; nq++) {
        bf16x8 bfm[2][2];
#pragma unroll
        for (int ks = 0; ks < 2; ks++) {
          int slot = ((ks << 2) | lgr) ^ sl7;
#pragma unroll
          for (int nn = 0; nn < 2; nn++)
            bfm[ks][nn] = *(const bf16x8*)&Bc[(wn * 64 + (nq * 2 + nn) * 16 + lrow) * 64 + slot * 8];
        }
        __builtin_amdgcn_s_setprio(1);
#pragma unroll
        for (int mm = 0; mm < MH; mm++)
#pragma unroll
          for (int nn = 0; nn < 2; nn++) {
            int m = mq * MH + mm, n = nq * 2 + nn;
            acc[m][n] = __builtin_amdgcn_mfma_f32_16x16x32_bf16(af[0][mm], bfm[0][nn], acc[m][n], 0, 0, 0);
            acc[m][n] = __builtin_amdgcn_mfma_f32_16x16x32_bf16(af[1][mm], bfm[1][nn], acc[m][n], 0, 0, 0);
          }
        __builtin_amdgcn_s_setprio(0);
      }
    }
    __builtin_amdgcn_sched_barrier(0);
    __builtin_amdgcn_s_barrier();
    __builtin_amdgcn_sched_barrier(0);
  }
#pragma unroll
  for (int n = 0; n < 4; n++) {
    int col = bn * 256 + wn * 64 + n * 16 + lrow;
    float bv = (MODE & 1) ? bias[col] : 0.0f;
    if (MODE & 16) {
      int c = col % 3;
      int hd = (col / 3) & 63;
      int h = col / 192;
      u16* dst = (c == 0) ? Kc : (c == 1) ? Qc : Vc;
#pragma unroll
      for (int m = 0; m < MFRAG; m++)
#pragma unroll
        for (int r = 0; r < 4; r++) {
          int row = bm * BM + wm * (BM / 2) + m * 16 + lgr * 4 + r;
          int bb = row >> 11, sIdx = row & 2047;
          dst[(((size_t)(bb * H_ + h)) * S_ + sIdx) * HD_ + hd] = f2bf(acc[m][n][r]);
        }
    } else {
#pragma unroll
      for (int m = 0; m < MFRAG; m++)
#pragma unroll
        for (int r = 0; r < 4; r++) {
          int row = bm * BM + wm * (BM / 2) + m * 16 + lgr * 4 + r;
          float v = acc[m][n][r] + bv;
          if (MODE & 2) v = gelu_f(v);
          if (MODE & 4) v += res[(size_t)row * N + col];
          if (MODE & 8) Cb[(size_t)row * N + col] = f2bf(v);
          else          Cf[(size_t)row * N + col] = v;
        }
    }
  }
}

// ---------------- attention helpers -------------------------------------------------------
// shared softmax+PV core operating on score regs s[NSUB]; V reader is a functor.
__device__ __forceinline__ void attn_softmax_update(
    f32x16* s, int NSUB_rt, float& mrun, float& lrun, f32x16 (&o)[2], int hi) {
  float pmax = -3.0e38f;
  for (int sub = 0; sub < NSUB_rt; sub++)
#pragma unroll
    for (int r = 0; r < 16; r++) pmax = fmaxf(pmax, s[sub][r]);
  pmax = fmaxf(pmax, __shfl_xor(pmax, 32));
  bool ok = (pmax * SCALE_ <= mrun + THR_);
  if (!__all(ok)) {
    float mnew = fmaxf(mrun, pmax * SCALE_);
    float corr = __builtin_amdgcn_exp2f(mrun - mnew);
    mrun = mnew;
    lrun *= corr;
#pragma unroll
    for (int r = 0; r < 16; r++) {
      float cr = __shfl(corr, ((r & 3) + 8 * (r >> 2)) + 4 * hi);
      o[0][r] *= cr;
      o[1][r] *= cr;
    }
  }
  float m = mrun;
  float lacc = 0.f;
  for (int sub = 0; sub < NSUB_rt; sub++)
#pragma unroll
    for (int r = 0; r < 16; r++) {
      float p = __builtin_amdgcn_exp2f(__builtin_fmaf(s[sub][r], SCALE_, -m));
      s[sub][r] = p;
      lacc += p;
    }
  lrun += lacc;
}

__device__ __forceinline__ void attn_pfrag(const f32x16& s, bf16x8& pa, bf16x8& pb) {
  u32 a0 = cvtpk_bf16(s[0], s[1]);
  u32 a1 = cvtpk_bf16(s[2], s[3]);
  u32 a2 = cvtpk_bf16(s[4], s[5]);
  u32 a3 = cvtpk_bf16(s[6], s[7]);
  swap32(a0, a2);
  swap32(a1, a3);
  u32 b0 = cvtpk_bf16(s[8], s[9]);
  u32 b1 = cvtpk_bf16(s[10], s[11]);
  u32 b2 = cvtpk_bf16(s[12], s[13]);
  u32 b3 = cvtpk_bf16(s[14], s[15]);
  swap32(b0, b2);
  swap32(b1, b3);
  u32x4 fa = {a0, a1, a2, a3};
  u32x4 fb = {b0, b1, b2, b3};
  pa = __builtin_bit_cast(bf16x8, fa);
  pb = __builtin_bit_cast(bf16x8, fb);
}

// tail chunk (global K/V), 32 keys, optional mask
template <bool MASK>
__device__ __forceinline__ void attn_chunk_tail(
    const u16* __restrict__ Kh, const u16* __restrict__ Vh,
    const bf16x8 (&qf)[4], f32x16 (&o)[2],
    float& mrun, float& lrun, int kb, int qrow, int hi, int ln31) {
  f32x16 s[1];
  f32x16 z = zero16();
  __builtin_amdgcn_s_setprio(1);
#pragma unroll
  for (int ks = 0; ks < 4; ks++) {
    bf16x8 kfr = *(const bf16x8*)(Kh + (size_t)(kb + ln31) * HD_ + ks * 16 + hi * 8);
    z = __builtin_amdgcn_mfma_f32_32x32x16_bf16(kfr, qf[ks], z, 0, 0, 0);
  }
  __builtin_amdgcn_s_setprio(0);
  if (MASK) {
#pragma unroll
    for (int r = 0; r < 16; r++) {
      int key = kb + (r & 3) + 8 * (r >> 2) + 4 * hi;
      if (key > qrow) z[r] = -3.0e38f;
    }
  }
  s[0] = z;
  attn_softmax_update(s, 1, mrun, lrun, o, hi);
  bf16x8 pa, pb;
  attn_pfrag(s[0], pa, pb);
  __builtin_amdgcn_s_setprio(1);
#pragma unroll
  for (int ht = 0; ht < 2; ht++) {
    const u16* vb = Vh + (size_t)(ht * 32 + ln31) * S_ + kb + hi * 8;
    bf16x8 v1 = *(const bf16x8*)(vb);
    bf16x8 v2 = *(const bf16x8*)(vb + 16);
    o[ht] = __builtin_amdgcn_mfma_f32_32x32x16_bf16(pa, v1, o[ht], 0, 0, 0);
    o[ht] = __builtin_amdgcn_mfma_f32_32x32x16_bf16(pb, v2, o[ht], 0, 0, 0);
  }
  __builtin_amdgcn_s_setprio(0);
}

// ---------------- causal flash attention: 8 waves/block, shared K/V LDS, dbuf + vmcnt ------
// Block = 256 q rows (8 waves x 32). K/V 64-key tiles staged to LDS by all 512 threads
// (XOR-swizzled source, linear dest); stage(kt+1) -> vmcnt(2) -> barrier -> compute -> barrier.
// Per-wave compute: 32x32 swapped-QK^T (col=q=lane&31, row=key=(r&3)+8*(r>>2)+4*hi),
// in-register softmax, cvtpk+permlane P-frags. Tails (diagonal) per wave from global.
__global__ __launch_bounds__(512) void attn_kernel(const u16* __restrict__ Q,
                                                   const u16* __restrict__ Kk,
                                                   const u16* __restrict__ Vt,
                                                   u16* __restrict__ ctx) {
  __shared__ __align__(16) u16 Kl[2][64 * 64];
  __shared__ __align__(16) u16 Vl[2][64 * 64];
  int t = threadIdx.x;
  int lane = t & 63, wid = t >> 6;
  int qblk = 7 - (int)(blockIdx.x >> 6);  // heavy q-panels first
  int bh = blockIdx.x & 63;
  int b = bh >> 4, h = bh & 15;
  const u16* Qh = Q + (size_t)bh * S_ * HD_;
  const u16* Kh = Kk + (size_t)bh * S_ * HD_;
  const u16* Vh = Vt + (size_t)bh * HD_ * S_;
  int qb = qblk * 256;
  int qbase = qb + wid * 32;
  int ln31 = lane & 31, hi = lane >> 5;
  int qrow = qbase + ln31;
  int l7 = ln31 & 7;

  // staging: thread t -> LDS row t>>3, linear slot t&7; source col slot XOR-swizzled
  int srow = t >> 3;
  int sslot = (t & 7) ^ (srow & 7);
  const u16* Ksrc = Kh + (size_t)srow * HD_ + sslot * 8;  // + kb*HD_
  const u16* Vsrc = Vh + (size_t)srow * S_ + sslot * 8;   // + kb

  bf16x8 qf[4];
#pragma unroll
  for (int ks = 0; ks < 4; ks++)
    qf[ks] = *(const bf16x8*)(Qh + (size_t)qrow * HD_ + ks * 16 + hi * 8);

  f32x16 o[2] = {zero16(), zero16()};
  float mrun = -1.0e30f, lrun = 0.f;

  int nf64 = qbase >> 6;       // this wave's full shared chunks
  int NT = (qb >> 6) + 3;      // block-wide shared chunks (max over waves)

  // prologue
  gl_lds16(Ksrc, &Kl[0][t * 8]);
  gl_lds16(Vsrc, &Vl[0][t * 8]);
  for (int kt = 0; kt < NT; kt++) {
    int cur = kt & 1;
    if (kt + 1 < NT) {
      int kb1 = (kt + 1) * 64;
      gl_lds16(Ksrc + (size_t)kb1 * HD_, &Kl[cur ^ 1][t * 8]);
      gl_lds16(Vsrc + kb1, &Vl[cur ^ 1][t * 8]);
      asm volatile("s_waitcnt vmcnt(2)" ::: "memory");
    } else {
      asm volatile("s_waitcnt vmcnt(0)" ::: "memory");
    }
    __builtin_amdgcn_sched_barrier(0);
    __builtin_amdgcn_s_barrier();
    __builtin_amdgcn_sched_barrier(0);
    if (kt < nf64) {
      const u16* Kc = &Kl[cur][0];
      const u16* Vc = &Vl[cur][0];
      f32x16 s[2];
#pragma unroll
      for (int sub = 0; sub < 2; sub++) {
        f32x16 z = zero16();
        __builtin_amdgcn_s_setprio(1);
#pragma unroll
        for (int ks = 0; ks < 4; ks++) {
          int kr = sub * 32 + ln31;
          int sl = (ks * 2 + hi) ^ l7;
          bf16x8 kfr = *(const bf16x8*)&Kc[kr * 64 + sl * 8];
          z = __builtin_amdgcn_mfma_f32_32x32x16_bf16(kfr, qf[ks], z, 0, 0, 0);
        }
        __builtin_amdgcn_s_setprio(0);
        s[sub] = z;
      }
      attn_softmax_update(s, 2, mrun, lrun, o, hi);
#pragma unroll
      for (int sub = 0; sub < 2; sub++) {
        bf16x8 pa, pb;
        attn_pfrag(s[sub], pa, pb);
        __builtin_amdgcn_s_setprio(1);
#pragma unroll
        for (int ht = 0; ht < 2; ht++) {
          int vr = ht * 32 + ln31;
          int s1 = (sub * 4 + hi) ^ (vr & 7);
          int s2 = (sub * 4 + hi + 2) ^ (vr & 7);
          bf16x8 v1 = *(const bf16x8*)&Vc[vr * 64 + s1 * 8];
          bf16x8 v2 = *(const bf16x8*)&Vc[vr * 64 + s2 * 8];
          o[ht] = __builtin_amdgcn_mfma_f32_32x32x16_bf16(pa, v1, o[ht], 0, 0, 0);
          o[ht] = __builtin_amdgcn_mfma_f32_32x32x16_bf16(pb, v2, o[ht], 0, 0, 0);
        }
        __builtin_amdgcn_s_setprio(0);
      }
    }
    __builtin_amdgcn_sched_barrier(0);
    __builtin_amdgcn_s_barrier();
    __builtin_amdgcn_sched_barrier(0);
  }

  // per-wave causal tails from global: [nf64*64, qbase) unmasked 32 + diagonal masked 32
  if (qbase & 32)
    attn_chunk_tail<false>(Kh, Vh, qf, o, mrun, lrun, qbase - 32, qrow, hi, ln31);
  attn_chunk_tail<true>(Kh, Vh, qf, o, mrun, lrun, qbase, qrow, hi, ln31);

  float l = lrun + __shfl_xor(lrun, 32);
  float inv = 1.0f / l;
#pragma unroll
  for (int r = 0; r < 16; r++) {
    float invr = __shfl(inv, ((r & 3) + 8 * (r >> 2)) + 4 * hi);
    int q = qbase + (r & 3) + 8 * (r >> 2) + 4 * hi;
    size_t base = ((size_t)b * S_ + q) * D_ + h * HD_;
    ctx[base + ln31] = f2bf(o[0][r] * invr);
    ctx[base + 32 + ln31] = f2bf(o[1][r] * invr);
  }
}

extern "C" void kernel_launch(void* const* d_in, const int* in_sizes, int n_in,
                              void* d_out, int out_size, void* d_ws, size_t ws_size,
                              hipStream_t stream) {
  const float* x = (const float*)d_in[0];
  const float* ln1w = (const float*)d_in[1];
  const float* ln1b = (const float*)d_in[2];
  const float* wqkv = (const float*)d_in[3];
  const float* wproj = (const float*)d_in[4];
  const float* bproj = (const float*)d_in[5];
  const float* ln2w = (const float*)d_in[6];
  const float* ln2b = (const float*)d_in[7];
  const float* wff1 = (const float*)d_in[8];
  const float* bff1 = (const float*)d_in[9];
  const float* wff2 = (const float*)d_in[10];
  const float* bff2 = (const float*)d_in[11];

  char* ws = (char*)d_ws;
  u16* wqkvT = (u16*)(ws + 0);                 //  6 MB  [3072][1024]
  u16* wprojT = (u16*)(ws + 6291456);          //  2 MB  [1024][1024]
  u16* wff1T = (u16*)(ws + 8388608);           //  8 MB  [4096][1024]
  u16* wff2T = (u16*)(ws + 16777216);          //  8 MB  [1024][4096]
  u16* h1 = (u16*)(ws + 25165824);             // 16 MB  [8192][1024]; dead after QKV gemm
  u16* Vt = (u16*)(ws + 25165824);             // 16 MB  [bh][64][S]; written after h1 dead
  u16* Qc = (u16*)(ws + 41943040);             // 16 MB  [bh][S][64]
  u16* Kc = (u16*)(ws + 58720256);             // 16 MB
  u16* Vc = (u16*)(ws + 75497472);             // 16 MB  [bh][S][64]
  u16* ctx = (u16*)(ws + 92274688);            // 16 MB  [8192][1024]
  float* x1 = (float*)(ws + 109051904);        // 32 MB  [8192][1024]
  u16* h2 = (u16*)(ws + 142606336);            // 16 MB
  u16* g = (u16*)(ws + 25165824);              // 64 MB  [8192][4096]; overlays h1/Vt/Qc/Kc/Vc
  float* outp = (float*)d_out;

  hipFuncSetAttribute((const void*)gemm256_kernel<16, 256>,
                      hipFuncAttributeMaxDynamicSharedMemorySize, 131072);
  hipFuncSetAttribute((const void*)gemm256_kernel<11, 256>,
                      hipFuncAttributeMaxDynamicSharedMemorySize, 131072);
  hipFuncSetAttribute((const void*)gemm256_kernel<5, 128>,
                      hipFuncAttributeMaxDynamicSharedMemorySize, 98304);

  wconv_kernel<<<(1024 / 32) * (3072 / 32), 256, 0, stream>>>(wqkv, wqkvT, 1024, 3072);
  wconv_kernel<<<(1024 / 32) * (1024 / 32), 256, 0, stream>>>(wproj, wprojT, 1024, 1024);
  wconv_kernel<<<(1024 / 32) * (4096 / 32), 256, 0, stream>>>(wff1, wff1T, 1024, 4096);
  wconv_kernel<<<(4096 / 32) * (1024 / 32), 256, 0, stream>>>(wff2, wff2T, 4096, 1024);

  ln_kernel<<<8192, 256, 0, stream>>>(x, ln1w, ln1b, h1);
  gemm256_kernel<16, 256><<<384, 512, 131072, stream>>>(h1, wqkvT, nullptr, nullptr,
                                                        nullptr, nullptr, Qc, Kc, Vc,
                                                        8192, 3072, 1024);
  vtrans_kernel<<<64 * 32, 256, 0, stream>>>(Vc, Vt);
  attn_kernel<<<8 * 64, 512, 0, stream>>>(Qc, Kc, Vt, ctx);
  gemm256_kernel<5, 128><<<256, 512, 98304, stream>>>(ctx, wprojT, bproj, x, x1, nullptr,
                                                      nullptr, nullptr, nullptr,
                                                      8192, 1024, 1024);
  ln_kernel<<<8192, 256, 0, stream>>>(x1, ln2w, ln2b, h2);
  gemm256_kernel<11, 256><<<512, 512, 131072, stream>>>(h2, wff1T, bff1, nullptr, nullptr, g,
                                                        nullptr, nullptr, nullptr,
                                                        8192, 4096, 1024);
  gemm256_kernel<5, 128><<<256, 512, 98304, stream>>>(g, wff2T, bff2, x1, outp, nullptr,
                                                      nullptr, nullptr, nullptr,
                                                      8192, 1024, 4096);
}